// Round 2
// baseline (588.933 us; speedup 1.0000x reference)
//
#include <hip/hip_runtime.h>

typedef unsigned short u16;
typedef short bfrag __attribute__((ext_vector_type(8)));   // 8 x bf16 (4 VGPR)
typedef float f32x4 __attribute__((ext_vector_type(4)));
typedef const __attribute__((address_space(1))) unsigned int* gp1_t;
typedef __attribute__((address_space(3))) unsigned int* lp3_t;

#define B_ 8192
#define H_ 1024
#define P_ 2048

__device__ __forceinline__ u16 f2bf(float f) {
  unsigned u = __builtin_bit_cast(unsigned, f);
  u += 0x7fffu + ((u >> 16) & 1u);
  return (u16)(u >> 16);
}
__device__ __forceinline__ float bf2f(u16 s) {
  return __builtin_bit_cast(float, (unsigned)s << 16);
}
__device__ __forceinline__ float sigm(float v) { return 1.f / (1.f + __expf(-v)); }

// ---------------- elementwise / reduction kernels ----------------

// fused: hidden f32 -> bf16 conversion + per-column sum|h| (for connection strength)
__global__ void k_hidact(const float* __restrict__ hidden, u16* __restrict__ hB,
                         float* __restrict__ act) {
  const int t = threadIdx.x;                 // 256
  const int r0 = blockIdx.x * 16;            // 512 blocks * 16 rows
  float s00 = 0, s01 = 0, s10 = 0, s11 = 0;
  for (int r = 0; r < 16; ++r) {
    const float* q = hidden + (size_t)(r0 + r) * H_;
    u16* o = hB + (size_t)(r0 + r) * H_;
    float2 v0 = *(const float2*)&q[2 * t];
    float2 v1 = *(const float2*)&q[512 + 2 * t];
    s00 += fabsf(v0.x); s01 += fabsf(v0.y);
    s10 += fabsf(v1.x); s11 += fabsf(v1.y);
    ushort2 o0, o1;
    o0.x = f2bf(v0.x); o0.y = f2bf(v0.y);
    o1.x = f2bf(v1.x); o1.y = f2bf(v1.y);
    *(ushort2*)&o[2 * t] = o0;
    *(ushort2*)&o[512 + 2 * t] = o1;
  }
  atomicAdd(&act[2 * t], s00); atomicAdd(&act[2 * t + 1], s01);
  atomicAdd(&act[512 + 2 * t], s10); atomicAdd(&act[512 + 2 * t + 1], s11);
}

__global__ void k_cs(const float* __restrict__ act, const float* __restrict__ strength,
                     const float* __restrict__ decay, const float* __restrict__ hist,
                     float* __restrict__ cs) {
  int h = blockIdx.x * 256 + threadIdx.x;
  float ch = hist[h] * decay[0] + act[h] * (1.f / (float)B_);
  cs[h] = strength[h] * sigm(ch);
}

struct ConvPs {
  const float* s[9];
  u16* d[9];
  int n4[9];
};

// all f32->bf16 conversions in one launch (8 weights + x), grid (2048, 9)
__global__ void k_conv9(ConvPs p) {
  const int e = blockIdx.y;
  const int n4 = p.n4[e];
  const float4* s = (const float4*)p.s[e];
  ushort4* d = (ushort4*)p.d[e];
  for (int i = blockIdx.x * 256 + threadIdx.x; i < n4; i += 2048 * 256) {
    float4 v = s[i];
    ushort4 o;
    o.x = f2bf(v.x); o.y = f2bf(v.y); o.z = f2bf(v.z); o.w = f2bf(v.w);
    d[i] = o;
  }
}

__global__ void k_rowmean(const float* __restrict__ hn, float* __restrict__ hp) {
  int row = blockIdx.x * 4 + (threadIdx.x >> 6);
  int lane = threadIdx.x & 63;
  const float* p = hn + (size_t)row * H_;
  float s = 0.f;
#pragma unroll
  for (int c = 0; c < H_ / 64; ++c) s += p[lane + c * 64];
#pragma unroll
  for (int o = 32; o; o >>= 1) s += __shfl_down(s, o);
  if (lane == 0) hp[row] = s * (1.f / (float)H_);
}

// ---------------- GEMM: C[M,N] = A[M,K] * B[N,K]^T, bf16 in, f32 acc ----------------
// A may be split in K: cols [0,K0) from A0 (row stride K0), [K0,K) from A1 (stride K-K0).

struct GemmPs {
  const u16* Bm[4];
  const float* bias[4];
  const float* hidden;   // f32 [B,1024]
  const float* update;   // f32 [B,1024]
  const float* cs;       // [1024]
  const u16* haB;        // bf16 ha (input to EPI2)
  u16* rhaB;             // bf16 reset*ha  (EPI2 z=0 out)
  float* out_f1;         // update f32     (EPI2 z=1 out)
  float* hn_f32;         // EPI3
  u16* hn_bf16;          // EPI3
  u16* haB_out;          // EPI1
  u16* out_b[4];         // EPI4 gate logits bf16 [B,2048]
};

template <int EPI>
__device__ __forceinline__ void epi(int row, int col, float v, int z, const GemmPs& e) {
  if constexpr (EPI == 1) {            // attention -> ha (bf16)
    v += e.bias[0][col];
    float a = sigm(v);
    size_t i = (size_t)row * H_ + col;
    e.haB_out[i] = f2bf(e.hidden[i] * a);
  } else if constexpr (EPI == 2) {     // z=0: reset*ha bf16; z=1: update f32
    size_t i = (size_t)row * H_ + col;
    if (z == 0) {
      v += e.bias[0][col];
      e.rhaB[i] = f2bf(v * bf2f(e.haB[i]));
    } else {
      v += e.bias[1][col];
      e.out_f1[i] = v;
    }
  } else if constexpr (EPI == 3) {     // new -> hidden_new
    v += e.bias[0][col];
    size_t i = (size_t)row * H_ + col;
    float u = e.update[i];
    float hn = (1.f - u) * e.hidden[i] + u * v * e.cs[col];
    e.hn_f32[i] = hn;
    e.hn_bf16[i] = f2bf(hn);
  } else {                             // gate logits bf16
    v += e.bias[z][col];
    e.out_b[z][(size_t)row * P_ + col] = f2bf(v);
  }
}

#define QUAD(Af, Bf, MO, NO)                                                         \
  do {                                                                               \
    _Pragma("unroll") for (int ks = 0; ks < 2; ++ks)                                 \
    _Pragma("unroll") for (int mi = 0; mi < 4; ++mi)                                 \
    _Pragma("unroll") for (int ni = 0; ni < 2; ++ni)                                 \
      acc[(MO) + mi][(NO) + ni] = __builtin_amdgcn_mfma_f32_16x16x32_bf16(           \
          Af[mi][ks], Bf[ni][ks], acc[(MO) + mi][(NO) + ni], 0, 0, 0);               \
  } while (0)

#define LGKM0()                                           \
  do {                                                    \
    asm volatile("s_waitcnt lgkmcnt(0)" ::: "memory");    \
    __builtin_amdgcn_sched_barrier(0);                    \
  } while (0)

// 256x256 tile, BK=64, 8 waves (2Mx4N), per-wave 128x64 out (acc[8][4] of 16x16).
// 4 phases per K-tile, 2 barriers/phase, setprio around MFMA, counted vmcnt(8)
// at phase 4 only (tile t+2 loads stay in flight across the boundary).
// LDS XOR-swizzle slot^(row&7), pre-swizzled global source (linear LDS dest).
template <int EPI>
__global__ __launch_bounds__(512, 2) void gemm8(const u16* __restrict__ A0,
                                                const u16* __restrict__ A1,
                                                int K0, int K, GemmPs e) {
  __shared__ u16 As[2][256 * 64];
  __shared__ u16 Bs[2][256 * 64];
  const int z = blockIdx.z;
  const u16* __restrict__ Bw = e.Bm[z];

  int bid = blockIdx.x;                         // XCD swizzle (gridDim.x % 8 == 0)
  const int cpx = gridDim.x >> 3;
  bid = (bid & 7) * cpx + (bid >> 3);
  const int m0 = (bid & 31) << 8;               // M = 8192 -> 32 row blocks
  const int n0 = (bid >> 5) << 8;

  const int tid = threadIdx.x;
  const int lane = tid & 63;
  const int w = tid >> 6;
  const int wr = w >> 2, wc = w & 3;
  const int r15 = lane & 15, g = lane >> 4, rx = lane & 7;

  const int srow = tid >> 3;                    // staging row 0..63 per round
  const int sslot8 = ((tid & 7) ^ (srow & 7)) << 3;

  f32x4 acc[8][4] = {};

  auto stage = [&](int buf, int kt) {
    const int k0 = kt << 6;
    const u16* Ab; int sA, kl;
    if (k0 < K0) { Ab = A0; sA = K0; kl = k0; }
    else         { Ab = A1; sA = K - K0; kl = k0 - K0; }
    const u16* pa = Ab + (size_t)(m0 + srow) * sA + kl + sslot8;
    const u16* pb = Bw + (size_t)(n0 + srow) * K + k0 + sslot8;
    u16* la = &As[buf][(w * 8) * 64];           // wave-uniform base, lane*16B implicit
    u16* lb = &Bs[buf][(w * 8) * 64];
#pragma unroll
    for (int r = 0; r < 4; ++r) {
      __builtin_amdgcn_global_load_lds((gp1_t)(pa + (size_t)(r * 64) * sA),
                                       (lp3_t)(la + r * 64 * 64), 16, 0, 0);
      __builtin_amdgcn_global_load_lds((gp1_t)(pb + (size_t)(r * 64) * K),
                                       (lp3_t)(lb + r * 64 * 64), 16, 0, 0);
    }
  };

  const int nt = K >> 6;
  stage(0, 0);
  stage(1, 1);
  asm volatile("s_waitcnt vmcnt(8)" ::: "memory");
  __builtin_amdgcn_s_barrier();

  bfrag af[4][2], b0[2][2], b1[2][2];

  for (int t = 0; t < nt; ++t) {
    const int buf = t & 1;
    // ---- phase 1: read A[0..3] (8) + B[0..1] (4); MFMA Q0
#pragma unroll
    for (int mi = 0; mi < 4; ++mi)
#pragma unroll
      for (int ks = 0; ks < 2; ++ks)
        af[mi][ks] = *(const bfrag*)&As[buf][(wr * 128 + mi * 16 + r15) * 64 +
                                            (((g + ks * 4) ^ rx) << 3)];
#pragma unroll
    for (int ni = 0; ni < 2; ++ni)
#pragma unroll
      for (int ks = 0; ks < 2; ++ks)
        b0[ni][ks] = *(const bfrag*)&Bs[buf][(wc * 64 + ni * 16 + r15) * 64 +
                                            (((g + ks * 4) ^ rx) << 3)];
    __builtin_amdgcn_s_barrier();
    LGKM0();
    __builtin_amdgcn_s_setprio(1);
    QUAD(af, b0, 0, 0);
    __builtin_amdgcn_s_setprio(0);
    __builtin_amdgcn_s_barrier();
    // ---- phase 2: read B[2..3] (4); MFMA Q1
#pragma unroll
    for (int ni = 0; ni < 2; ++ni)
#pragma unroll
      for (int ks = 0; ks < 2; ++ks)
        b1[ni][ks] = *(const bfrag*)&Bs[buf][(wc * 64 + 32 + ni * 16 + r15) * 64 +
                                            (((g + ks * 4) ^ rx) << 3)];
    __builtin_amdgcn_s_barrier();
    LGKM0();
    __builtin_amdgcn_s_setprio(1);
    QUAD(af, b1, 0, 2);
    __builtin_amdgcn_s_setprio(0);
    __builtin_amdgcn_s_barrier();
    // ---- phase 3: read A[4..7] (8); MFMA Q2
#pragma unroll
    for (int mi = 0; mi < 4; ++mi)
#pragma unroll
      for (int ks = 0; ks < 2; ++ks)
        af[mi][ks] = *(const bfrag*)&As[buf][(wr * 128 + 64 + mi * 16 + r15) * 64 +
                                            (((g + ks * 4) ^ rx) << 3)];
    __builtin_amdgcn_s_barrier();
    LGKM0();
    __builtin_amdgcn_s_setprio(1);
    QUAD(af, b0, 4, 0);
    __builtin_amdgcn_s_setprio(0);
    __builtin_amdgcn_s_barrier();
    // ---- phase 4: stage tile t+2 (8 loads) into buf just freed; counted vmcnt; MFMA Q3
    if (t + 2 < nt) {
      stage(buf, t + 2);
      asm volatile("s_waitcnt vmcnt(8)" ::: "memory");
    } else {
      asm volatile("s_waitcnt vmcnt(0)" ::: "memory");
    }
    __builtin_amdgcn_s_barrier();
    __builtin_amdgcn_s_setprio(1);
    QUAD(af, b1, 4, 2);
    __builtin_amdgcn_s_setprio(0);
    __builtin_amdgcn_s_barrier();
  }

  // C/D layout: col = lane&15, row = (lane>>4)*4 + reg   [m89-verified]
#pragma unroll
  for (int mi = 0; mi < 8; ++mi)
#pragma unroll
    for (int ni = 0; ni < 4; ++ni)
#pragma unroll
      for (int rr = 0; rr < 4; ++rr)
        epi<EPI>(m0 + wr * 128 + mi * 16 + g * 4 + rr,
                 n0 + wc * 64 + ni * 16 + r15, acc[mi][ni][rr], z, e);
}

// ---------------- final: softmax(addr), sigmoids, memory_new, hidden_final ----------------

__global__ __launch_bounds__(256) void k_final(
    const u16* __restrict__ aL, const u16* __restrict__ rL,
    const u16* __restrict__ wL, const u16* __restrict__ fL,
    const float* __restrict__ pm, const float* __restrict__ hn,
    const float* __restrict__ hp, float* __restrict__ outH, float* __restrict__ outM) {
  __shared__ float sl[P_];
  __shared__ float red[8];
  const int row = blockIdx.x, t = threadIdx.x;
  const size_t base = (size_t)row * P_;

  float lm = -3.4e38f;
  for (int p = t; p < P_; p += 256) {
    float v = bf2f(aL[base + p]);
    sl[p] = v;
    lm = fmaxf(lm, v);
  }
#pragma unroll
  for (int o = 32; o; o >>= 1) lm = fmaxf(lm, __shfl_down(lm, o));
  if ((t & 63) == 0) red[t >> 6] = lm;
  __syncthreads();
  const float bmax = fmaxf(fmaxf(red[0], red[1]), fmaxf(red[2], red[3]));

  float ls = 0.f;
  for (int p = t; p < P_; p += 256) {
    float ev = __expf(sl[p] - bmax);
    sl[p] = ev;
    ls += ev;
  }
#pragma unroll
  for (int o = 32; o; o >>= 1) ls += __shfl_down(ls, o);
  if ((t & 63) == 0) red[4 + (t >> 6)] = ls;
  __syncthreads();
  const float inv = 1.f / (red[4] + red[5] + red[6] + red[7]);
  const float hpv = hp[row];

  float rs = 0.f;
  for (int p = t; p < P_; p += 256) {
    float a = sl[p] * inv;
    float fo = sigm(bf2f(fL[base + p]));
    float wv = sigm(bf2f(wL[base + p]));
    float rd = sigm(bf2f(rL[base + p]));
    float mem = fo * pm[base + p] + wv * hpv * a;
    outM[base + p] = mem;
    rs += rd * mem;
  }
#pragma unroll
  for (int o = 32; o; o >>= 1) rs += __shfl_down(rs, o);
  __syncthreads();
  if ((t & 63) == 0) red[t >> 6] = rs;
  __syncthreads();
  const float mean = (red[0] + red[1] + red[2] + red[3]) * (1.f / (float)P_);
  const size_t hb = (size_t)row * H_;
  for (int h = t; h < H_; h += 256) outH[hb + h] = hn[hb + h] + mean;
}

// ---------------- host ----------------

extern "C" void kernel_launch(void* const* d_in, const int* in_sizes, int n_in,
                              void* d_out, int out_size, void* d_ws, size_t ws_size,
                              hipStream_t stream) {
  (void)in_sizes; (void)n_in; (void)out_size; (void)ws_size;
  const float* x       = (const float*)d_in[0];
  const float* hidden  = (const float*)d_in[1];
  const float* pm      = (const float*)d_in[2];
  const float* Wa      = (const float*)d_in[3];
  const float* ba      = (const float*)d_in[4];
  const float* Wr      = (const float*)d_in[5];
  const float* br      = (const float*)d_in[6];
  const float* Wu      = (const float*)d_in[7];
  const float* bu      = (const float*)d_in[8];
  const float* Wn      = (const float*)d_in[9];
  const float* bn      = (const float*)d_in[10];
  const float* Wread   = (const float*)d_in[11];
  const float* bread   = (const float*)d_in[12];
  const float* Wwrite  = (const float*)d_in[13];
  const float* bwrite  = (const float*)d_in[14];
  const float* Wforget = (const float*)d_in[15];
  const float* bforget = (const float*)d_in[16];
  const float* Waddr   = (const float*)d_in[17];
  const float* baddr   = (const float*)d_in[18];
  const float* cstr    = (const float*)d_in[19];
  const float* cdecay  = (const float*)d_in[20];
  const float* chist   = (const float*)d_in[21];

  char* wsp = (char*)d_ws;
  auto take = [&](size_t n) { char* p = wsp; wsp += (n + 255) & ~(size_t)255; return p; };
  float* act    = (float*)take((size_t)H_ * 4);
  float* cs     = (float*)take((size_t)H_ * 4);
  float* hp     = (float*)take((size_t)B_ * 4);
  u16* hiddenB  = (u16*)take((size_t)B_ * H_ * 2);      // later reused as hidden_new bf16
  u16* xB       = (u16*)take((size_t)B_ * H_ * 2);
  u16* haB      = (u16*)take((size_t)B_ * H_ * 2);
  u16* rhaB     = (u16*)take((size_t)B_ * H_ * 2);
  u16* WaB      = (u16*)take((size_t)H_ * H_ * 2);
  u16* WrB      = (u16*)take((size_t)H_ * 2048 * 2);
  u16* WuB      = (u16*)take((size_t)H_ * 2048 * 2);
  u16* WnB      = (u16*)take((size_t)H_ * 2048 * 2);
  u16* WadB     = (u16*)take((size_t)P_ * H_ * 2);
  u16* WrdB     = (u16*)take((size_t)P_ * H_ * 2);
  u16* WwrB     = (u16*)take((size_t)P_ * H_ * 2);
  u16* WfgB     = (u16*)take((size_t)P_ * H_ * 2);
  float* update = (float*)take((size_t)B_ * H_ * 4);
  float* hnf    = (float*)take((size_t)B_ * H_ * 4);
  u16* gAd      = (u16*)take((size_t)B_ * P_ * 2);
  u16* gRd      = (u16*)take((size_t)B_ * P_ * 2);
  u16* gWr      = (u16*)take((size_t)B_ * P_ * 2);
  u16* gFg      = (u16*)take((size_t)B_ * P_ * 2);

  float* outH = (float*)d_out;
  float* outM = outH + (size_t)B_ * H_;

  // connection strength (fused hidden->bf16 + column |h| sums)
  hipMemsetAsync(act, 0, (size_t)H_ * 4, stream);
  k_hidact<<<dim3(512), dim3(256), 0, stream>>>(hidden, hiddenB, act);
  k_cs<<<dim3(4), dim3(256), 0, stream>>>(act, cstr, cdecay, chist, cs);

  // all conversions in one launch
  {
    ConvPs p;
    const float* ss[9] = {Wa, Wr, Wu, Wn, Waddr, Wread, Wwrite, Wforget, x};
    u16* dd[9] = {WaB, WrB, WuB, WnB, WadB, WrdB, WwrB, WfgB, xB};
    int nn[9] = {H_ * H_ / 4, H_ * 2048 / 4, H_ * 2048 / 4, H_ * 2048 / 4,
                 P_ * H_ / 4, P_ * H_ / 4, P_ * H_ / 4, P_ * H_ / 4, B_ * H_ / 4};
    for (int i = 0; i < 9; ++i) { p.s[i] = ss[i]; p.d[i] = dd[i]; p.n4[i] = nn[i]; }
    k_conv9<<<dim3(2048, 9), dim3(256), 0, stream>>>(p);
  }

  // GEMM 1: attention -> ha bf16
  {
    GemmPs e{};
    e.Bm[0] = WaB; e.bias[0] = ba; e.hidden = hidden; e.haB_out = haB;
    gemm8<1><<<dim3(128, 1, 1), dim3(512), 0, stream>>>(hiddenB, hiddenB, 1024, 1024, e);
  }
  // GEMM 2/3: z=0 reset -> rha bf16 (reads haB); z=1 update f32. A = [x | ha]
  {
    GemmPs e{};
    e.Bm[0] = WrB; e.Bm[1] = WuB; e.bias[0] = br; e.bias[1] = bu;
    e.haB = haB; e.rhaB = rhaB; e.out_f1 = update;
    gemm8<2><<<dim3(128, 1, 2), dim3(512), 0, stream>>>(xB, haB, 1024, 2048, e);
  }
  // GEMM 4: new -> hidden_new (f32 + bf16). A = [x | rha]
  {
    GemmPs e{};
    e.Bm[0] = WnB; e.bias[0] = bn; e.hidden = hidden; e.update = update; e.cs = cs;
    e.hn_f32 = hnf; e.hn_bf16 = hiddenB;
    gemm8<3><<<dim3(128, 1, 1), dim3(512), 0, stream>>>(xB, rhaB, 1024, 2048, e);
  }
  k_rowmean<<<dim3(2048), dim3(256), 0, stream>>>(hnf, hp);
  // GEMMs 5-8: gate logits (addr, read, write, forget)
  {
    GemmPs e{};
    e.Bm[0] = WadB; e.Bm[1] = WrdB; e.Bm[2] = WwrB; e.Bm[3] = WfgB;
    e.bias[0] = baddr; e.bias[1] = bread; e.bias[2] = bwrite; e.bias[3] = bforget;
    e.out_b[0] = gAd; e.out_b[1] = gRd; e.out_b[2] = gWr; e.out_b[3] = gFg;
    gemm8<4><<<dim3(256, 1, 4), dim3(512), 0, stream>>>(hiddenB, hiddenB, 1024, 1024, e);
  }
  // final fused softmax / gates / outputs
  k_final<<<dim3(B_), dim3(256), 0, stream>>>(gAd, gRd, gWr, gFg, pm, hnf, hp, outH, outM);
}

// Round 3
// 451.006 us; speedup vs baseline: 1.3058x; 1.3058x over previous
//
#include <hip/hip_runtime.h>

typedef unsigned short u16;
typedef short bfrag __attribute__((ext_vector_type(8)));   // 8 x bf16 (4 VGPR)
typedef float f32x4 __attribute__((ext_vector_type(4)));
typedef const __attribute__((address_space(1))) unsigned int* gp1_t;
typedef __attribute__((address_space(3))) unsigned int* lp3_t;

#define B_ 8192
#define H_ 1024
#define P_ 2048

__device__ __forceinline__ u16 f2bf(float f) {
  unsigned u = __builtin_bit_cast(unsigned, f);
  u += 0x7fffu + ((u >> 16) & 1u);
  return (u16)(u >> 16);
}
__device__ __forceinline__ float bf2f(u16 s) {
  return __builtin_bit_cast(float, (unsigned)s << 16);
}
__device__ __forceinline__ float sigm(float v) { return 1.f / (1.f + __expf(-v)); }

// ---------------- elementwise / reduction kernels ----------------

__global__ void k_hidact(const float* __restrict__ hidden, u16* __restrict__ hB,
                         float* __restrict__ act) {
  const int t = threadIdx.x;                 // 256
  const int r0 = blockIdx.x * 16;            // 512 blocks * 16 rows
  float s00 = 0, s01 = 0, s10 = 0, s11 = 0;
  for (int r = 0; r < 16; ++r) {
    const float* q = hidden + (size_t)(r0 + r) * H_;
    u16* o = hB + (size_t)(r0 + r) * H_;
    float2 v0 = *(const float2*)&q[2 * t];
    float2 v1 = *(const float2*)&q[512 + 2 * t];
    s00 += fabsf(v0.x); s01 += fabsf(v0.y);
    s10 += fabsf(v1.x); s11 += fabsf(v1.y);
    ushort2 o0, o1;
    o0.x = f2bf(v0.x); o0.y = f2bf(v0.y);
    o1.x = f2bf(v1.x); o1.y = f2bf(v1.y);
    *(ushort2*)&o[2 * t] = o0;
    *(ushort2*)&o[512 + 2 * t] = o1;
  }
  atomicAdd(&act[2 * t], s00); atomicAdd(&act[2 * t + 1], s01);
  atomicAdd(&act[512 + 2 * t], s10); atomicAdd(&act[512 + 2 * t + 1], s11);
}

__global__ void k_cs(const float* __restrict__ act, const float* __restrict__ strength,
                     const float* __restrict__ decay, const float* __restrict__ hist,
                     float* __restrict__ cs) {
  int h = blockIdx.x * 256 + threadIdx.x;
  float ch = hist[h] * decay[0] + act[h] * (1.f / (float)B_);
  cs[h] = strength[h] * sigm(ch);
}

struct ConvPs {
  const float* s[9];
  u16* d[9];
  int n4[9];
};

__global__ void k_conv9(ConvPs p) {
  const int e = blockIdx.y;
  const int n4 = p.n4[e];
  const float4* s = (const float4*)p.s[e];
  ushort4* d = (ushort4*)p.d[e];
  for (int i = blockIdx.x * 256 + threadIdx.x; i < n4; i += 2048 * 256) {
    float4 v = s[i];
    ushort4 o;
    o.x = f2bf(v.x); o.y = f2bf(v.y); o.z = f2bf(v.z); o.w = f2bf(v.w);
    d[i] = o;
  }
}

__global__ void k_rowmean(const float* __restrict__ hn, float* __restrict__ hp) {
  int row = blockIdx.x * 4 + (threadIdx.x >> 6);
  int lane = threadIdx.x & 63;
  const float* p = hn + (size_t)row * H_;
  float s = 0.f;
#pragma unroll
  for (int c = 0; c < H_ / 64; ++c) s += p[lane + c * 64];
#pragma unroll
  for (int o = 32; o; o >>= 1) s += __shfl_down(s, o);
  if (lane == 0) hp[row] = s * (1.f / (float)H_);
}

// ---------------- GEMM epilogues ----------------

struct GemmPs {
  const u16* Bm[4];
  const float* bias[4];
  const float* hidden;   // f32 [B,1024]
  const float* update;   // f32 [B,1024]
  const float* cs;       // [1024]
  const u16* haB;        // bf16 ha (input to EPI2 z=0)
  u16* rhaB;             // bf16 reset*ha  (EPI2 z=0 out)
  float* out_f1;         // update f32     (EPI2 z=1 out)
  float* hn_f32;         // EPI3
  u16* hn_bf16;          // EPI3
  u16* haB_out;          // EPI1
  u16* out_b[4];         // EPI4 gate logits bf16 [B,2048]
};

template <int EPI>
__device__ __forceinline__ void epi(int row, int col, float v, int z, const GemmPs& e) {
  if constexpr (EPI == 1) {            // attention -> ha (bf16)
    v += e.bias[0][col];
    float a = sigm(v);
    size_t i = (size_t)row * H_ + col;
    e.haB_out[i] = f2bf(e.hidden[i] * a);
  } else if constexpr (EPI == 2) {     // z=0: reset*ha bf16; z=1: update f32
    size_t i = (size_t)row * H_ + col;
    if (z == 0) {
      v += e.bias[0][col];
      e.rhaB[i] = f2bf(v * bf2f(e.haB[i]));
    } else {
      v += e.bias[1][col];
      e.out_f1[i] = v;
    }
  } else if constexpr (EPI == 3) {     // new -> hidden_new
    v += e.bias[0][col];
    size_t i = (size_t)row * H_ + col;
    float u = e.update[i];
    float hn = (1.f - u) * e.hidden[i] + u * v * e.cs[col];
    e.hn_f32[i] = hn;
    e.hn_bf16[i] = f2bf(hn);
  } else {                             // gate logits bf16
    v += e.bias[z][col];
    e.out_b[z][(size_t)row * P_ + col] = f2bf(v);
  }
}

// ---------------- gemm_bt: proven 128x128 / BK=64 / 4-wave structure ----------------
// C[M,N] = A[M,K] * B[N,K]^T. A split in K: cols [0,K0) from A0 (stride K0),
// [K0,K) from A1 (stride K-K0). LDS XOR-swizzle slot^(row&7) via pre-swizzled source.

template <int EPI>
__global__ __launch_bounds__(256, 2) void gemm_bt(const u16* __restrict__ A0,
                                                  const u16* __restrict__ A1,
                                                  int K0, int K, GemmPs e) {
  const int z = blockIdx.z;
  const u16* __restrict__ Bm = e.Bm[z];
  __shared__ u16 As[128 * 64];
  __shared__ u16 Bs[128 * 64];
  const int lane = threadIdx.x & 63;
  const int w = threadIdx.x >> 6;
  const int wr = w >> 1, wc = w & 1;
  const int m0 = blockIdx.x * 128, n0 = blockIdx.y * 128;

  f32x4 acc[4][4] = {};

  const int rA = lane >> 3;
  const int srcSlot8 = ((lane & 7) ^ (rA & 7)) << 3;

  const int g = lane >> 4;
  const int r15 = lane & 15;
  const int rx = lane & 7;

  for (int k0 = 0; k0 < K; k0 += 64) {
    const u16* Ab; int sA, kl;
    if (k0 < K0) { Ab = A0; sA = K0; kl = k0; }
    else         { Ab = A1; sA = K - K0; kl = k0 - K0; }
    const u16* pA = Ab + (size_t)(m0 + w * 32 + rA) * sA + kl + srcSlot8;
    const u16* pB = Bm + (size_t)(n0 + w * 32 + rA) * K + k0 + srcSlot8;
#pragma unroll
    for (int j = 0; j < 4; ++j) {
      __builtin_amdgcn_global_load_lds((gp1_t)(pA + (size_t)j * 8 * sA),
                                       (lp3_t)&As[(w * 32 + j * 8) * 64], 16, 0, 0);
      __builtin_amdgcn_global_load_lds((gp1_t)(pB + (size_t)j * 8 * K),
                                       (lp3_t)&Bs[(w * 32 + j * 8) * 64], 16, 0, 0);
    }
    asm volatile("s_waitcnt vmcnt(0)" ::: "memory");
    __syncthreads();
#pragma unroll
    for (int kk = 0; kk < 64; kk += 32) {
      const int slot = g + (kk >> 3);
      const int cswz = ((slot ^ rx) << 3);
      bfrag af[4], bq[4];
#pragma unroll
      for (int i = 0; i < 4; ++i) {
        af[i] = *(const bfrag*)&As[(wr * 64 + i * 16 + r15) * 64 + cswz];
        bq[i] = *(const bfrag*)&Bs[(wc * 64 + i * 16 + r15) * 64 + cswz];
      }
#pragma unroll
      for (int mi = 0; mi < 4; ++mi)
#pragma unroll
        for (int ni = 0; ni < 4; ++ni)
          acc[mi][ni] = __builtin_amdgcn_mfma_f32_16x16x32_bf16(af[mi], bq[ni], acc[mi][ni], 0, 0, 0);
    }
    __syncthreads();
  }

#pragma unroll
  for (int mi = 0; mi < 4; ++mi)
#pragma unroll
    for (int ni = 0; ni < 4; ++ni)
#pragma unroll
      for (int r = 0; r < 4; ++r)
        epi<EPI>(m0 + wr * 64 + mi * 16 + g * 4 + r,
                 n0 + wc * 64 + ni * 16 + r15, acc[mi][ni][r], z, e);
}

// ---------------- gemm8: 256x256 8-wave 4-phase pipelined (gate GEMM only) ----------------

#define QUAD(Af, Bf, MO, NO)                                                         \
  do {                                                                               \
    _Pragma("unroll") for (int ks = 0; ks < 2; ++ks)                                 \
    _Pragma("unroll") for (int mi = 0; mi < 4; ++mi)                                 \
    _Pragma("unroll") for (int ni = 0; ni < 2; ++ni)                                 \
      acc[(MO) + mi][(NO) + ni] = __builtin_amdgcn_mfma_f32_16x16x32_bf16(           \
          Af[mi][ks], Bf[ni][ks], acc[(MO) + mi][(NO) + ni], 0, 0, 0);               \
  } while (0)

#define LGKM0()                                           \
  do {                                                    \
    asm volatile("s_waitcnt lgkmcnt(0)" ::: "memory");    \
    __builtin_amdgcn_sched_barrier(0);                    \
  } while (0)

// XCD-locality swizzle: xcd = bid&7 owns m-blocks [xcd*4, xcd*4+4) (2 MB A WS @K=1024),
// sweeping n within. Requires M = 8192 (32 m-blocks), gridDim.x = 32*nn.
template <int EPI>
__global__ __launch_bounds__(512, 2) void gemm8(const u16* __restrict__ A0,
                                                const u16* __restrict__ A1,
                                                int K0, int K, GemmPs e) {
  __shared__ u16 As[2][256 * 64];
  __shared__ u16 Bs[2][256 * 64];
  const int z = blockIdx.z;
  const u16* __restrict__ Bw = e.Bm[z];

  const int bid = blockIdx.x;
  const int xcd = bid & 7, jj = bid >> 3;
  const int m0 = (xcd * 4 + (jj & 3)) << 8;
  const int n0 = (jj >> 2) << 8;

  const int tid = threadIdx.x;
  const int lane = tid & 63;
  const int w = tid >> 6;
  const int wr = w >> 2, wc = w & 3;
  const int r15 = lane & 15, g = lane >> 4, rx = lane & 7;

  const int srow = tid >> 3;
  const int sslot8 = ((tid & 7) ^ (srow & 7)) << 3;

  f32x4 acc[8][4] = {};

  auto stageA = [&](int buf, int kt) {
    const int k0 = kt << 6;
    const u16* Ab; int sA, kl;
    if (k0 < K0) { Ab = A0; sA = K0; kl = k0; }
    else         { Ab = A1; sA = K - K0; kl = k0 - K0; }
    const u16* pa = Ab + (size_t)(m0 + srow) * sA + kl + sslot8;
    u16* la = &As[buf][(w * 8) * 64];
#pragma unroll
    for (int r = 0; r < 4; ++r)
      __builtin_amdgcn_global_load_lds((gp1_t)(pa + (size_t)(r * 64) * sA),
                                       (lp3_t)(la + r * 64 * 64), 16, 0, 0);
  };
  auto stageB = [&](int buf, int kt) {
    const int k0 = kt << 6;
    const u16* pb = Bw + (size_t)(n0 + srow) * K + k0 + sslot8;
    u16* lb = &Bs[buf][(w * 8) * 64];
#pragma unroll
    for (int r = 0; r < 4; ++r)
      __builtin_amdgcn_global_load_lds((gp1_t)(pb + (size_t)(r * 64) * K),
                                       (lp3_t)(lb + r * 64 * 64), 16, 0, 0);
  };

  const int nt = K >> 6;
  stageA(0, 0); stageB(0, 0);
  stageA(1, 1); stageB(1, 1);
  asm volatile("s_waitcnt vmcnt(8)" ::: "memory");
  __builtin_amdgcn_s_barrier();

  bfrag af[4][2], b0[2][2], b1[2][2];

  for (int t = 0; t < nt; ++t) {
    const int buf = t & 1;
    // ---- phase 1: read A half-0 (8) + B[0..1] (4); MFMA Q0
#pragma unroll
    for (int mi = 0; mi < 4; ++mi)
#pragma unroll
      for (int ks = 0; ks < 2; ++ks)
        af[mi][ks] = *(const bfrag*)&As[buf][(wr * 128 + mi * 16 + r15) * 64 +
                                            (((g + ks * 4) ^ rx) << 3)];
#pragma unroll
    for (int ni = 0; ni < 2; ++ni)
#pragma unroll
      for (int ks = 0; ks < 2; ++ks)
        b0[ni][ks] = *(const bfrag*)&Bs[buf][(wc * 64 + ni * 16 + r15) * 64 +
                                            (((g + ks * 4) ^ rx) << 3)];
    __builtin_amdgcn_s_barrier();
    LGKM0();
    __builtin_amdgcn_s_setprio(1);
    QUAD(af, b0, 0, 0);
    __builtin_amdgcn_s_setprio(0);
    __builtin_amdgcn_s_barrier();
    // ---- phase 2: read B[2..3] (4); MFMA Q1
#pragma unroll
    for (int ni = 0; ni < 2; ++ni)
#pragma unroll
      for (int ks = 0; ks < 2; ++ks)
        b1[ni][ks] = *(const bfrag*)&Bs[buf][(wc * 64 + 32 + ni * 16 + r15) * 64 +
                                            (((g + ks * 4) ^ rx) << 3)];
    __builtin_amdgcn_s_barrier();
    LGKM0();
    __builtin_amdgcn_s_setprio(1);
    QUAD(af, b1, 0, 2);
    __builtin_amdgcn_s_setprio(0);
    __builtin_amdgcn_s_barrier();
    // ---- phase 3: stage B(t+2) into freed Bs[buf]; read A half-1 (8); MFMA Q2
    if (t + 2 < nt) stageB(buf, t + 2);
#pragma unroll
    for (int mi = 0; mi < 4; ++mi)
#pragma unroll
      for (int ks = 0; ks < 2; ++ks)
        af[mi][ks] = *(const bfrag*)&As[buf][(wr * 128 + 64 + mi * 16 + r15) * 64 +
                                            (((g + ks * 4) ^ rx) << 3)];
    __builtin_amdgcn_s_barrier();
    LGKM0();
    __builtin_amdgcn_s_setprio(1);
    QUAD(af, b0, 4, 0);
    __builtin_amdgcn_s_setprio(0);
    __builtin_amdgcn_s_barrier();
    // ---- phase 4: stage A(t+2) into freed As[buf]; counted vmcnt; MFMA Q3
    if (t + 2 < nt) {
      stageA(buf, t + 2);
      asm volatile("s_waitcnt vmcnt(8)" ::: "memory");
    } else {
      asm volatile("s_waitcnt vmcnt(0)" ::: "memory");
    }
    __builtin_amdgcn_s_barrier();
    __builtin_amdgcn_s_setprio(1);
    QUAD(af, b1, 4, 2);
    __builtin_amdgcn_s_setprio(0);
    __builtin_amdgcn_s_barrier();
  }

#pragma unroll
  for (int mi = 0; mi < 8; ++mi)
#pragma unroll
    for (int ni = 0; ni < 4; ++ni)
#pragma unroll
      for (int rr = 0; rr < 4; ++rr)
        epi<EPI>(m0 + wr * 128 + mi * 16 + g * 4 + rr,
                 n0 + wc * 64 + ni * 16 + r15, acc[mi][ni][rr], z, e);
}

// ---------------- final: softmax(addr), sigmoids, memory_new, hidden_final ----------------

__global__ __launch_bounds__(256) void k_final(
    const u16* __restrict__ aL, const u16* __restrict__ rL,
    const u16* __restrict__ wL, const u16* __restrict__ fL,
    const float* __restrict__ pm, const float* __restrict__ hn,
    const float* __restrict__ hp, float* __restrict__ outH, float* __restrict__ outM) {
  __shared__ float sl[P_];
  __shared__ float red[8];
  const int row = blockIdx.x, t = threadIdx.x;
  const size_t base = (size_t)row * P_;

  float lm = -3.4e38f;
  for (int p = t; p < P_; p += 256) {
    float v = bf2f(aL[base + p]);
    sl[p] = v;
    lm = fmaxf(lm, v);
  }
#pragma unroll
  for (int o = 32; o; o >>= 1) lm = fmaxf(lm, __shfl_down(lm, o));
  if ((t & 63) == 0) red[t >> 6] = lm;
  __syncthreads();
  const float bmax = fmaxf(fmaxf(red[0], red[1]), fmaxf(red[2], red[3]));

  float ls = 0.f;
  for (int p = t; p < P_; p += 256) {
    float ev = __expf(sl[p] - bmax);
    sl[p] = ev;
    ls += ev;
  }
#pragma unroll
  for (int o = 32; o; o >>= 1) ls += __shfl_down(ls, o);
  if ((t & 63) == 0) red[4 + (t >> 6)] = ls;
  __syncthreads();
  const float inv = 1.f / (red[4] + red[5] + red[6] + red[7]);
  const float hpv = hp[row];

  float rs = 0.f;
  for (int p = t; p < P_; p += 256) {
    float a = sl[p] * inv;
    float fo = sigm(bf2f(fL[base + p]));
    float wv = sigm(bf2f(wL[base + p]));
    float rd = sigm(bf2f(rL[base + p]));
    float mem = fo * pm[base + p] + wv * hpv * a;
    outM[base + p] = mem;
    rs += rd * mem;
  }
#pragma unroll
  for (int o = 32; o; o >>= 1) rs += __shfl_down(rs, o);
  __syncthreads();
  if ((t & 63) == 0) red[t >> 6] = rs;
  __syncthreads();
  const float mean = (red[0] + red[1] + red[2] + red[3]) * (1.f / (float)P_);
  const size_t hb = (size_t)row * H_;
  for (int h = t; h < H_; h += 256) outH[hb + h] = hn[hb + h] + mean;
}

// ---------------- host ----------------

extern "C" void kernel_launch(void* const* d_in, const int* in_sizes, int n_in,
                              void* d_out, int out_size, void* d_ws, size_t ws_size,
                              hipStream_t stream) {
  (void)in_sizes; (void)n_in; (void)out_size; (void)ws_size;
  const float* x       = (const float*)d_in[0];
  const float* hidden  = (const float*)d_in[1];
  const float* pm      = (const float*)d_in[2];
  const float* Wa      = (const float*)d_in[3];
  const float* ba      = (const float*)d_in[4];
  const float* Wr      = (const float*)d_in[5];
  const float* br      = (const float*)d_in[6];
  const float* Wu      = (const float*)d_in[7];
  const float* bu      = (const float*)d_in[8];
  const float* Wn      = (const float*)d_in[9];
  const float* bn      = (const float*)d_in[10];
  const float* Wread   = (const float*)d_in[11];
  const float* bread   = (const float*)d_in[12];
  const float* Wwrite  = (const float*)d_in[13];
  const float* bwrite  = (const float*)d_in[14];
  const float* Wforget = (const float*)d_in[15];
  const float* bforget = (const float*)d_in[16];
  const float* Waddr   = (const float*)d_in[17];
  const float* baddr   = (const float*)d_in[18];
  const float* cstr    = (const float*)d_in[19];
  const float* cdecay  = (const float*)d_in[20];
  const float* chist   = (const float*)d_in[21];

  char* wsp = (char*)d_ws;
  auto take = [&](size_t n) { char* p = wsp; wsp += (n + 255) & ~(size_t)255; return p; };
  float* act    = (float*)take((size_t)H_ * 4);
  float* cs     = (float*)take((size_t)H_ * 4);
  float* hp     = (float*)take((size_t)B_ * 4);
  u16* hiddenB  = (u16*)take((size_t)B_ * H_ * 2);      // later reused as hidden_new bf16
  u16* xB       = (u16*)take((size_t)B_ * H_ * 2);
  u16* haB      = (u16*)take((size_t)B_ * H_ * 2);
  u16* rhaB     = (u16*)take((size_t)B_ * H_ * 2);
  u16* WaB      = (u16*)take((size_t)H_ * H_ * 2);
  u16* WrB      = (u16*)take((size_t)H_ * 2048 * 2);
  u16* WuB      = (u16*)take((size_t)H_ * 2048 * 2);
  u16* WnB      = (u16*)take((size_t)H_ * 2048 * 2);
  u16* WadB     = (u16*)take((size_t)P_ * H_ * 2);
  u16* WrdB     = (u16*)take((size_t)P_ * H_ * 2);
  u16* WwrB     = (u16*)take((size_t)P_ * H_ * 2);
  u16* WfgB     = (u16*)take((size_t)P_ * H_ * 2);
  float* update = (float*)take((size_t)B_ * H_ * 4);
  float* hnf    = (float*)take((size_t)B_ * H_ * 4);
  u16* gAd      = (u16*)take((size_t)B_ * P_ * 2);
  u16* gRd      = (u16*)take((size_t)B_ * P_ * 2);
  u16* gWr      = (u16*)take((size_t)B_ * P_ * 2);
  u16* gFg      = (u16*)take((size_t)B_ * P_ * 2);

  float* outH = (float*)d_out;
  float* outM = outH + (size_t)B_ * H_;

  // connection strength (fused hidden->bf16 + column |h| sums)
  hipMemsetAsync(act, 0, (size_t)H_ * 4, stream);
  k_hidact<<<dim3(512), dim3(256), 0, stream>>>(hidden, hiddenB, act);
  k_cs<<<dim3(4), dim3(256), 0, stream>>>(act, cstr, cdecay, chist, cs);

  // all conversions in one launch
  {
    ConvPs p;
    const float* ss[9] = {Wa, Wr, Wu, Wn, Waddr, Wread, Wwrite, Wforget, x};
    u16* dd[9] = {WaB, WrB, WuB, WnB, WadB, WrdB, WwrB, WfgB, xB};
    int nn[9] = {H_ * H_ / 4, H_ * 2048 / 4, H_ * 2048 / 4, H_ * 2048 / 4,
                 P_ * H_ / 4, P_ * H_ / 4, P_ * H_ / 4, P_ * H_ / 4, B_ * H_ / 4};
    for (int i = 0; i < 9; ++i) { p.s[i] = ss[i]; p.d[i] = dd[i]; p.n4[i] = nn[i]; }
    k_conv9<<<dim3(2048, 9), dim3(256), 0, stream>>>(p);
  }

  // GEMM 1: attention -> ha bf16 (proven 128^2 structure)
  {
    GemmPs e{};
    e.Bm[0] = WaB; e.bias[0] = ba; e.hidden = hidden; e.haB_out = haB;
    gemm_bt<1><<<dim3(64, 8, 1), dim3(256), 0, stream>>>(hiddenB, hiddenB, 1024, 1024, e);
  }
  // GEMM 2/3: z=0 reset -> rha bf16; z=1 update f32. A = [x | ha] (128^2 structure)
  {
    GemmPs e{};
    e.Bm[0] = WrB; e.Bm[1] = WuB; e.bias[0] = br; e.bias[1] = bu;
    e.haB = haB; e.rhaB = rhaB; e.out_f1 = update;
    gemm_bt<2><<<dim3(64, 8, 2), dim3(256), 0, stream>>>(xB, haB, 1024, 2048, e);
  }
  // GEMM 4: new -> hidden_new (f32 + bf16). A = [x | rha] (128^2 structure)
  {
    GemmPs e{};
    e.Bm[0] = WnB; e.bias[0] = bn; e.hidden = hidden; e.update = update; e.cs = cs;
    e.hn_f32 = hnf; e.hn_bf16 = hiddenB;
    gemm_bt<3><<<dim3(64, 8, 1), dim3(256), 0, stream>>>(xB, rhaB, 1024, 2048, e);
  }
  k_rowmean<<<dim3(2048), dim3(256), 0, stream>>>(hnf, hp);
  // GEMMs 5-8: gate logits — 8-phase 256^2 pipelined kernel (A/B experiment)
  {
    GemmPs e{};
    e.Bm[0] = WadB; e.Bm[1] = WrdB; e.Bm[2] = WwrB; e.Bm[3] = WfgB;
    e.bias[0] = baddr; e.bias[1] = bread; e.bias[2] = bwrite; e.bias[3] = bforget;
    e.out_b[0] = gAd; e.out_b[1] = gRd; e.out_b[2] = gWr; e.out_b[3] = gFg;
    gemm8<4><<<dim3(256, 1, 4), dim3(512), 0, stream>>>(hiddenB, hiddenB, 1024, 1024, e);
  }
  // final fused softmax / gates / outputs
  k_final<<<dim3(B_), dim3(256), 0, stream>>>(gAd, gRd, gWr, gFg, pm, hnf, hp, outH, outM);
}

// Round 4
// 449.036 us; speedup vs baseline: 1.3115x; 1.0044x over previous
//
#include <hip/hip_runtime.h>

typedef unsigned short u16;
typedef short bfrag __attribute__((ext_vector_type(8)));   // 8 x bf16 (4 VGPR)
typedef float f32x4 __attribute__((ext_vector_type(4)));
typedef const __attribute__((address_space(1))) unsigned int* gp1_t;
typedef __attribute__((address_space(3))) unsigned int* lp3_t;

#define B_ 8192
#define H_ 1024
#define P_ 2048

__device__ __forceinline__ u16 f2bf(float f) {
  unsigned u = __builtin_bit_cast(unsigned, f);
  u += 0x7fffu + ((u >> 16) & 1u);
  return (u16)(u >> 16);
}
__device__ __forceinline__ float bf2f(u16 s) {
  return __builtin_bit_cast(float, (unsigned)s << 16);
}
__device__ __forceinline__ float sigm(float v) { return 1.f / (1.f + __expf(-v)); }

// ---------------- elementwise / reduction kernels ----------------

__global__ void k_hidact(const float* __restrict__ hidden, u16* __restrict__ hB,
                         float* __restrict__ act) {
  const int t = threadIdx.x;                 // 256
  const int r0 = blockIdx.x * 16;            // 512 blocks * 16 rows
  float s00 = 0, s01 = 0, s10 = 0, s11 = 0;
  for (int r = 0; r < 16; ++r) {
    const float* q = hidden + (size_t)(r0 + r) * H_;
    u16* o = hB + (size_t)(r0 + r) * H_;
    float2 v0 = *(const float2*)&q[2 * t];
    float2 v1 = *(const float2*)&q[512 + 2 * t];
    s00 += fabsf(v0.x); s01 += fabsf(v0.y);
    s10 += fabsf(v1.x); s11 += fabsf(v1.y);
    ushort2 o0, o1;
    o0.x = f2bf(v0.x); o0.y = f2bf(v0.y);
    o1.x = f2bf(v1.x); o1.y = f2bf(v1.y);
    *(ushort2*)&o[2 * t] = o0;
    *(ushort2*)&o[512 + 2 * t] = o1;
  }
  atomicAdd(&act[2 * t], s00); atomicAdd(&act[2 * t + 1], s01);
  atomicAdd(&act[512 + 2 * t], s10); atomicAdd(&act[512 + 2 * t + 1], s11);
}

__global__ void k_cs(const float* __restrict__ act, const float* __restrict__ strength,
                     const float* __restrict__ decay, const float* __restrict__ hist,
                     float* __restrict__ cs) {
  int h = blockIdx.x * 256 + threadIdx.x;
  float ch = hist[h] * decay[0] + act[h] * (1.f / (float)B_);
  cs[h] = strength[h] * sigm(ch);
}

struct ConvPs {
  const float* s[9];
  u16* d[9];
  int n4[9];
};

__global__ void k_conv9(ConvPs p) {
  const int e = blockIdx.y;
  const int n4 = p.n4[e];
  const float4* s = (const float4*)p.s[e];
  ushort4* d = (ushort4*)p.d[e];
  for (int i = blockIdx.x * 256 + threadIdx.x; i < n4; i += 2048 * 256) {
    float4 v = s[i];
    ushort4 o;
    o.x = f2bf(v.x); o.y = f2bf(v.y); o.z = f2bf(v.z); o.w = f2bf(v.w);
    d[i] = o;
  }
}

__global__ void k_rowmean(const float* __restrict__ hn, float* __restrict__ hp) {
  int row = blockIdx.x * 4 + (threadIdx.x >> 6);
  int lane = threadIdx.x & 63;
  const float4* p4 = (const float4*)(hn + (size_t)row * H_);
  float s = 0.f;
#pragma unroll
  for (int c = 0; c < 4; ++c) {
    float4 v = p4[lane + c * 64];
    s += v.x + v.y + v.z + v.w;
  }
#pragma unroll
  for (int o = 32; o; o >>= 1) s += __shfl_down(s, o);
  if (lane == 0) hp[row] = s * (1.f / (float)H_);
}

// ---------------- GEMM epilogues (vectorized: lane owns 4 consecutive cols) ----------------

struct GemmPs {
  const u16* Bm[4];
  const float* bias[4];
  const float* hidden;   // f32 [B,1024]
  const float* update;   // f32 [B,1024]
  const float* cs;       // [1024]
  const u16* haB;        // bf16 ha (input to EPI2 z=0)
  u16* rhaB;             // bf16 reset*ha  (EPI2 z=0 out)
  float* out_f1;         // update f32     (EPI2 z=1 out)
  float* hn_f32;         // EPI3
  u16* hn_bf16;          // EPI3
  u16* haB_out;          // EPI1
  u16* out_b[4];         // EPI4 gate logits bf16 [B,2048]
};

template <int EPI>
__device__ __forceinline__ void epiV(int row, int col0, f32x4 v, int z, const GemmPs& e) {
  if constexpr (EPI == 1) {            // attention -> ha (bf16)
    float4 bi = *(const float4*)&e.bias[0][col0];
    size_t i = (size_t)row * H_ + col0;
    float4 hd = *(const float4*)&e.hidden[i];
    ushort4 o;
    o.x = f2bf(hd.x * sigm(v[0] + bi.x));
    o.y = f2bf(hd.y * sigm(v[1] + bi.y));
    o.z = f2bf(hd.z * sigm(v[2] + bi.z));
    o.w = f2bf(hd.w * sigm(v[3] + bi.w));
    *(ushort4*)&e.haB_out[i] = o;
  } else if constexpr (EPI == 2) {     // z=0: reset*ha bf16; z=1: update f32
    size_t i = (size_t)row * H_ + col0;
    if (z == 0) {
      float4 bi = *(const float4*)&e.bias[0][col0];
      ushort4 h = *(const ushort4*)&e.haB[i];
      ushort4 o;
      o.x = f2bf((v[0] + bi.x) * bf2f(h.x));
      o.y = f2bf((v[1] + bi.y) * bf2f(h.y));
      o.z = f2bf((v[2] + bi.z) * bf2f(h.z));
      o.w = f2bf((v[3] + bi.w) * bf2f(h.w));
      *(ushort4*)&e.rhaB[i] = o;
    } else {
      float4 bi = *(const float4*)&e.bias[1][col0];
      float4 o;
      o.x = v[0] + bi.x; o.y = v[1] + bi.y; o.z = v[2] + bi.z; o.w = v[3] + bi.w;
      *(float4*)&e.out_f1[i] = o;
    }
  } else if constexpr (EPI == 3) {     // new -> hidden_new
    float4 bi = *(const float4*)&e.bias[0][col0];
    size_t i = (size_t)row * H_ + col0;
    float4 u4 = *(const float4*)&e.update[i];
    float4 hd = *(const float4*)&e.hidden[i];
    float4 c4 = *(const float4*)&e.cs[col0];
    float4 hn;
    hn.x = (1.f - u4.x) * hd.x + u4.x * (v[0] + bi.x) * c4.x;
    hn.y = (1.f - u4.y) * hd.y + u4.y * (v[1] + bi.y) * c4.y;
    hn.z = (1.f - u4.z) * hd.z + u4.z * (v[2] + bi.z) * c4.z;
    hn.w = (1.f - u4.w) * hd.w + u4.w * (v[3] + bi.w) * c4.w;
    *(float4*)&e.hn_f32[i] = hn;
    ushort4 o;
    o.x = f2bf(hn.x); o.y = f2bf(hn.y); o.z = f2bf(hn.z); o.w = f2bf(hn.w);
    *(ushort4*)&e.hn_bf16[i] = o;
  } else {                             // gate logits bf16
    float4 bi = *(const float4*)&e.bias[z][col0];
    ushort4 o;
    o.x = f2bf(v[0] + bi.x); o.y = f2bf(v[1] + bi.y);
    o.z = f2bf(v[2] + bi.z); o.w = f2bf(v[3] + bi.w);
    *(ushort4*)&e.out_b[z][(size_t)row * P_ + col0] = o;
  }
}

// ---------------- gemm_bt: proven 128x128 / BK=64 / 4-wave structure ----------------
// C[M,N] = A[M,K] * B[N,K]^T. Operand-SWAPPED mfma(b,a): lane holds m=r15 (lane&15),
// n = g*4 + reg (4 consecutive cols) -> vector epilogue stores.

template <int EPI>
__global__ __launch_bounds__(256, 2) void gemm_bt(const u16* __restrict__ A0,
                                                  const u16* __restrict__ A1,
                                                  int K0, int K, GemmPs e) {
  const int z = blockIdx.z;
  const u16* __restrict__ Bm = e.Bm[z];
  __shared__ u16 As[128 * 64];
  __shared__ u16 Bs[128 * 64];
  const int lane = threadIdx.x & 63;
  const int w = threadIdx.x >> 6;
  const int wr = w >> 1, wc = w & 1;
  const int m0 = blockIdx.x * 128, n0 = blockIdx.y * 128;

  f32x4 acc[4][4] = {};

  const int rA = lane >> 3;
  const int srcSlot8 = ((lane & 7) ^ (rA & 7)) << 3;

  const int g = lane >> 4;
  const int r15 = lane & 15;
  const int rx = lane & 7;

  for (int k0 = 0; k0 < K; k0 += 64) {
    const u16* Ab; int sA, kl;
    if (k0 < K0) { Ab = A0; sA = K0; kl = k0; }
    else         { Ab = A1; sA = K - K0; kl = k0 - K0; }
    const u16* pA = Ab + (size_t)(m0 + w * 32 + rA) * sA + kl + srcSlot8;
    const u16* pB = Bm + (size_t)(n0 + w * 32 + rA) * K + k0 + srcSlot8;
#pragma unroll
    for (int j = 0; j < 4; ++j) {
      __builtin_amdgcn_global_load_lds((gp1_t)(pA + (size_t)j * 8 * sA),
                                       (lp3_t)&As[(w * 32 + j * 8) * 64], 16, 0, 0);
      __builtin_amdgcn_global_load_lds((gp1_t)(pB + (size_t)j * 8 * K),
                                       (lp3_t)&Bs[(w * 32 + j * 8) * 64], 16, 0, 0);
    }
    asm volatile("s_waitcnt vmcnt(0)" ::: "memory");
    __syncthreads();
#pragma unroll
    for (int kk = 0; kk < 64; kk += 32) {
      const int slot = g + (kk >> 3);
      const int cswz = ((slot ^ rx) << 3);
      bfrag af[4], bq[4];
#pragma unroll
      for (int i = 0; i < 4; ++i) {
        af[i] = *(const bfrag*)&As[(wr * 64 + i * 16 + r15) * 64 + cswz];
        bq[i] = *(const bfrag*)&Bs[(wc * 64 + i * 16 + r15) * 64 + cswz];
      }
#pragma unroll
      for (int mi = 0; mi < 4; ++mi)
#pragma unroll
        for (int ni = 0; ni < 4; ++ni)
          acc[mi][ni] = __builtin_amdgcn_mfma_f32_16x16x32_bf16(bq[ni], af[mi], acc[mi][ni], 0, 0, 0);
    }
    __syncthreads();
  }

  // swapped layout: m = r15 + mi*16, n = g*4 + reg + ni*16 (4 consecutive cols per lane)
#pragma unroll
  for (int mi = 0; mi < 4; ++mi)
#pragma unroll
    for (int ni = 0; ni < 4; ++ni)
      epiV<EPI>(m0 + wr * 64 + mi * 16 + r15,
                n0 + wc * 64 + ni * 16 + g * 4, acc[mi][ni], z, e);
}

// ---------------- gemm8: 256x256 8-wave 4-phase pipelined (gate GEMM only) ----------------

#define QUAD(Af, Bf, MO, NO)                                                         \
  do {                                                                               \
    _Pragma("unroll") for (int ks = 0; ks < 2; ++ks)                                 \
    _Pragma("unroll") for (int mi = 0; mi < 4; ++mi)                                 \
    _Pragma("unroll") for (int ni = 0; ni < 2; ++ni)                                 \
      acc[(MO) + mi][(NO) + ni] = __builtin_amdgcn_mfma_f32_16x16x32_bf16(           \
          Bf[ni][ks], Af[mi][ks], acc[(MO) + mi][(NO) + ni], 0, 0, 0);               \
  } while (0)

#define LGKM0()                                           \
  do {                                                    \
    asm volatile("s_waitcnt lgkmcnt(0)" ::: "memory");    \
    __builtin_amdgcn_sched_barrier(0);                    \
  } while (0)

// XCD-locality swizzle: xcd = bid&7 owns m-blocks [xcd*4, xcd*4+4) (2 MB A WS @K=1024).
// Staging spread 0/2/4/2 per phase: A bands {0,2} retire after ph1 -> stage ph2;
// B after ph2 -> stage ph3; A bands {1,3} after ph3 -> stage ph4 + counted vmcnt(8).
template <int EPI>
__global__ __launch_bounds__(512, 2) void gemm8(const u16* __restrict__ A0,
                                                const u16* __restrict__ A1,
                                                int K0, int K, GemmPs e) {
  __shared__ u16 As[2][256 * 64];
  __shared__ u16 Bs[2][256 * 64];
  const int z = blockIdx.z;
  const u16* __restrict__ Bw = e.Bm[z];

  const int bid = blockIdx.x;
  const int xcd = bid & 7, jj = bid >> 3;
  const int m0 = (xcd * 4 + (jj & 3)) << 8;
  const int n0 = (jj >> 2) << 8;

  const int tid = threadIdx.x;
  const int lane = tid & 63;
  const int w = tid >> 6;
  const int wr = w >> 2, wc = w & 3;
  const int r15 = lane & 15, g = lane >> 4, rx = lane & 7;

  const int srow = tid >> 3;
  const int sslot8 = ((tid & 7) ^ (srow & 7)) << 3;

  f32x4 acc[8][4] = {};

  auto stageA1 = [&](int buf, int kt, int r) {   // one 64-row band of A
    const int k0 = kt << 6;
    const u16* Ab; int sA, kl;
    if (k0 < K0) { Ab = A0; sA = K0; kl = k0; }
    else         { Ab = A1; sA = K - K0; kl = k0 - K0; }
    const u16* pa = Ab + (size_t)(m0 + srow + r * 64) * sA + kl + sslot8;
    __builtin_amdgcn_global_load_lds((gp1_t)pa,
                                     (lp3_t)&As[buf][(w * 8 + r * 64) * 64], 16, 0, 0);
  };
  auto stageB1 = [&](int buf, int kt, int r) {   // one 64-row band of B
    const int k0 = kt << 6;
    const u16* pb = Bw + (size_t)(n0 + srow + r * 64) * K + k0 + sslot8;
    __builtin_amdgcn_global_load_lds((gp1_t)pb,
                                     (lp3_t)&Bs[buf][(w * 8 + r * 64) * 64], 16, 0, 0);
  };

  const int nt = K >> 6;
#pragma unroll
  for (int r = 0; r < 4; ++r) { stageA1(0, 0, r); stageB1(0, 0, r); }
#pragma unroll
  for (int r = 0; r < 4; ++r) { stageA1(1, 1, r); stageB1(1, 1, r); }
  asm volatile("s_waitcnt vmcnt(8)" ::: "memory");
  __builtin_amdgcn_s_barrier();

  bfrag af[4][2], b0[2][2], b1[2][2];

  for (int t = 0; t < nt; ++t) {
    const int buf = t & 1;
    const bool pf = (t + 2 < nt);
    // ---- phase 1: read A half-0 (8) + B[0..1] (4); MFMA Q0
#pragma unroll
    for (int mi = 0; mi < 4; ++mi)
#pragma unroll
      for (int ks = 0; ks < 2; ++ks)
        af[mi][ks] = *(const bfrag*)&As[buf][(wr * 128 + mi * 16 + r15) * 64 +
                                            (((g + ks * 4) ^ rx) << 3)];
#pragma unroll
    for (int ni = 0; ni < 2; ++ni)
#pragma unroll
      for (int ks = 0; ks < 2; ++ks)
        b0[ni][ks] = *(const bfrag*)&Bs[buf][(wc * 64 + ni * 16 + r15) * 64 +
                                            (((g + ks * 4) ^ rx) << 3)];
    __builtin_amdgcn_s_barrier();
    LGKM0();
    __builtin_amdgcn_s_setprio(1);
    QUAD(af, b0, 0, 0);
    __builtin_amdgcn_s_setprio(0);
    __builtin_amdgcn_s_barrier();
    // ---- phase 2: read B[2..3] (4); stage A bands {0,2} of t+2; MFMA Q1
#pragma unroll
    for (int ni = 0; ni < 2; ++ni)
#pragma unroll
      for (int ks = 0; ks < 2; ++ks)
        b1[ni][ks] = *(const bfrag*)&Bs[buf][(wc * 64 + 32 + ni * 16 + r15) * 64 +
                                            (((g + ks * 4) ^ rx) << 3)];
    if (pf) { stageA1(buf, t + 2, 0); stageA1(buf, t + 2, 2); }
    __builtin_amdgcn_s_barrier();
    LGKM0();
    __builtin_amdgcn_s_setprio(1);
    QUAD(af, b1, 0, 2);
    __builtin_amdgcn_s_setprio(0);
    __builtin_amdgcn_s_barrier();
    // ---- phase 3: read A half-1 (8); stage B bands {0..3} of t+2; MFMA Q2
#pragma unroll
    for (int mi = 0; mi < 4; ++mi)
#pragma unroll
      for (int ks = 0; ks < 2; ++ks)
        af[mi][ks] = *(const bfrag*)&As[buf][(wr * 128 + 64 + mi * 16 + r15) * 64 +
                                            (((g + ks * 4) ^ rx) << 3)];
    if (pf) {
      stageB1(buf, t + 2, 0); stageB1(buf, t + 2, 1);
      stageB1(buf, t + 2, 2); stageB1(buf, t + 2, 3);
    }
    __builtin_amdgcn_s_barrier();
    LGKM0();
    __builtin_amdgcn_s_setprio(1);
    QUAD(af, b0, 4, 0);
    __builtin_amdgcn_s_setprio(0);
    __builtin_amdgcn_s_barrier();
    // ---- phase 4: stage A bands {1,3} of t+2; counted vmcnt(8); MFMA Q3
    if (pf) {
      stageA1(buf, t + 2, 1); stageA1(buf, t + 2, 3);
      asm volatile("s_waitcnt vmcnt(8)" ::: "memory");
    } else {
      asm volatile("s_waitcnt vmcnt(0)" ::: "memory");
    }
    __builtin_amdgcn_s_barrier();
    __builtin_amdgcn_s_setprio(1);
    QUAD(af, b1, 4, 2);
    __builtin_amdgcn_s_setprio(0);
    __builtin_amdgcn_s_barrier();
  }

  // swapped layout: m = r15 + mi*16, n = g*4 + reg + ni*16
#pragma unroll
  for (int mi = 0; mi < 8; ++mi)
#pragma unroll
    for (int ni = 0; ni < 4; ++ni)
      epiV<EPI>(m0 + wr * 128 + mi * 16 + r15,
                n0 + wc * 64 + ni * 16 + g * 4, acc[mi][ni], z, e);
}

// ---------------- final: softmax(addr), sigmoids, memory_new, hidden_final ----------------
// single pass: each thread owns 8 consecutive P-columns in registers.

__global__ __launch_bounds__(256) void k_final(
    const u16* __restrict__ aL, const u16* __restrict__ rL,
    const u16* __restrict__ wL, const u16* __restrict__ fL,
    const float* __restrict__ pm, const float* __restrict__ hn,
    const float* __restrict__ hp, float* __restrict__ outH, float* __restrict__ outM) {
  __shared__ float red[8];
  const int row = blockIdx.x, t = threadIdx.x;
  const size_t base = (size_t)row * P_ + t * 8;

  ushort4 a0 = *(const ushort4*)&aL[base];
  ushort4 a1 = *(const ushort4*)&aL[base + 4];
  float av[8] = {bf2f(a0.x), bf2f(a0.y), bf2f(a0.z), bf2f(a0.w),
                 bf2f(a1.x), bf2f(a1.y), bf2f(a1.z), bf2f(a1.w)};
  float lm = av[0];
#pragma unroll
  for (int j = 1; j < 8; ++j) lm = fmaxf(lm, av[j]);
#pragma unroll
  for (int o = 32; o; o >>= 1) lm = fmaxf(lm, __shfl_xor(lm, o));
  if ((t & 63) == 0) red[t >> 6] = lm;
  __syncthreads();
  const float bmax = fmaxf(fmaxf(red[0], red[1]), fmaxf(red[2], red[3]));

  float ev[8];
  float ls = 0.f;
#pragma unroll
  for (int j = 0; j < 8; ++j) { ev[j] = __expf(av[j] - bmax); ls += ev[j]; }
#pragma unroll
  for (int o = 32; o; o >>= 1) ls += __shfl_xor(ls, o);
  if ((t & 63) == 0) red[4 + (t >> 6)] = ls;
  __syncthreads();
  const float inv = 1.f / (red[4] + red[5] + red[6] + red[7]);
  const float hpv = hp[row];

  ushort4 r0 = *(const ushort4*)&rL[base], r1 = *(const ushort4*)&rL[base + 4];
  ushort4 w0 = *(const ushort4*)&wL[base], w1 = *(const ushort4*)&wL[base + 4];
  ushort4 f0 = *(const ushort4*)&fL[base], f1 = *(const ushort4*)&fL[base + 4];
  float4 p0 = *(const float4*)&pm[base], p1 = *(const float4*)&pm[base + 4];
  float rv[8] = {bf2f(r0.x), bf2f(r0.y), bf2f(r0.z), bf2f(r0.w),
                 bf2f(r1.x), bf2f(r1.y), bf2f(r1.z), bf2f(r1.w)};
  float wv[8] = {bf2f(w0.x), bf2f(w0.y), bf2f(w0.z), bf2f(w0.w),
                 bf2f(w1.x), bf2f(w1.y), bf2f(w1.z), bf2f(w1.w)};
  float fv[8] = {bf2f(f0.x), bf2f(f0.y), bf2f(f0.z), bf2f(f0.w),
                 bf2f(f1.x), bf2f(f1.y), bf2f(f1.z), bf2f(f1.w)};
  float pv[8] = {p0.x, p0.y, p0.z, p0.w, p1.x, p1.y, p1.z, p1.w};
  float mem[8];
  float rs = 0.f;
#pragma unroll
  for (int j = 0; j < 8; ++j) {
    mem[j] = sigm(fv[j]) * pv[j] + sigm(wv[j]) * hpv * (ev[j] * inv);
    rs += sigm(rv[j]) * mem[j];
  }
  float4 m0v = {mem[0], mem[1], mem[2], mem[3]};
  float4 m1v = {mem[4], mem[5], mem[6], mem[7]};
  *(float4*)&outM[base] = m0v;
  *(float4*)&outM[base + 4] = m1v;
#pragma unroll
  for (int o = 32; o; o >>= 1) rs += __shfl_xor(rs, o);
  __syncthreads();
  if ((t & 63) == 0) red[t >> 6] = rs;
  __syncthreads();
  const float mean = (red[0] + red[1] + red[2] + red[3]) * (1.f / (float)P_);
  const size_t hb = (size_t)row * H_ + t * 4;
  float4 h4 = *(const float4*)&hn[hb];
  h4.x += mean; h4.y += mean; h4.z += mean; h4.w += mean;
  *(float4*)&outH[hb] = h4;
}

// ---------------- host ----------------

extern "C" void kernel_launch(void* const* d_in, const int* in_sizes, int n_in,
                              void* d_out, int out_size, void* d_ws, size_t ws_size,
                              hipStream_t stream) {
  (void)in_sizes; (void)n_in; (void)out_size; (void)ws_size;
  const float* x       = (const float*)d_in[0];
  const float* hidden  = (const float*)d_in[1];
  const float* pm      = (const float*)d_in[2];
  const float* Wa      = (const float*)d_in[3];
  const float* ba      = (const float*)d_in[4];
  const float* Wr      = (const float*)d_in[5];
  const float* br      = (const float*)d_in[6];
  const float* Wu      = (const float*)d_in[7];
  const float* bu      = (const float*)d_in[8];
  const float* Wn      = (const float*)d_in[9];
  const float* bn      = (const float*)d_in[10];
  const float* Wread   = (const float*)d_in[11];
  const float* bread   = (const float*)d_in[12];
  const float* Wwrite  = (const float*)d_in[13];
  const float* bwrite  = (const float*)d_in[14];
  const float* Wforget = (const float*)d_in[15];
  const float* bforget = (const float*)d_in[16];
  const float* Waddr   = (const float*)d_in[17];
  const float* baddr   = (const float*)d_in[18];
  const float* cstr    = (const float*)d_in[19];
  const float* cdecay  = (const float*)d_in[20];
  const float* chist   = (const float*)d_in[21];

  char* wsp = (char*)d_ws;
  auto take = [&](size_t n) { char* p = wsp; wsp += (n + 255) & ~(size_t)255; return p; };
  float* act    = (float*)take((size_t)H_ * 4);
  float* cs     = (float*)take((size_t)H_ * 4);
  float* hp     = (float*)take((size_t)B_ * 4);
  u16* hiddenB  = (u16*)take((size_t)B_ * H_ * 2);      // later reused as hidden_new bf16
  u16* xB       = (u16*)take((size_t)B_ * H_ * 2);
  u16* haB      = (u16*)take((size_t)B_ * H_ * 2);
  u16* rhaB     = (u16*)take((size_t)B_ * H_ * 2);
  u16* WaB      = (u16*)take((size_t)H_ * H_ * 2);
  u16* WrB      = (u16*)take((size_t)H_ * 2048 * 2);
  u16* WuB      = (u16*)take((size_t)H_ * 2048 * 2);
  u16* WnB      = (u16*)take((size_t)H_ * 2048 * 2);
  u16* WadB     = (u16*)take((size_t)P_ * H_ * 2);
  u16* WrdB     = (u16*)take((size_t)P_ * H_ * 2);
  u16* WwrB     = (u16*)take((size_t)P_ * H_ * 2);
  u16* WfgB     = (u16*)take((size_t)P_ * H_ * 2);
  float* update = (float*)take((size_t)B_ * H_ * 4);
  float* hnf    = (float*)take((size_t)B_ * H_ * 4);
  u16* gAd      = (u16*)take((size_t)B_ * P_ * 2);
  u16* gRd      = (u16*)take((size_t)B_ * P_ * 2);
  u16* gWr      = (u16*)take((size_t)B_ * P_ * 2);
  u16* gFg      = (u16*)take((size_t)B_ * P_ * 2);

  float* outH = (float*)d_out;
  float* outM = outH + (size_t)B_ * H_;

  // connection strength (fused hidden->bf16 + column |h| sums)
  hipMemsetAsync(act, 0, (size_t)H_ * 4, stream);
  k_hidact<<<dim3(512), dim3(256), 0, stream>>>(hidden, hiddenB, act);
  k_cs<<<dim3(4), dim3(256), 0, stream>>>(act, cstr, cdecay, chist, cs);

  // all conversions in one launch
  {
    ConvPs p;
    const float* ss[9] = {Wa, Wr, Wu, Wn, Waddr, Wread, Wwrite, Wforget, x};
    u16* dd[9] = {WaB, WrB, WuB, WnB, WadB, WrdB, WwrB, WfgB, xB};
    int nn[9] = {H_ * H_ / 4, H_ * 2048 / 4, H_ * 2048 / 4, H_ * 2048 / 4,
                 P_ * H_ / 4, P_ * H_ / 4, P_ * H_ / 4, P_ * H_ / 4, B_ * H_ / 4};
    for (int i = 0; i < 9; ++i) { p.s[i] = ss[i]; p.d[i] = dd[i]; p.n4[i] = nn[i]; }
    k_conv9<<<dim3(2048, 9), dim3(256), 0, stream>>>(p);
  }

  // GEMM 1: attention -> ha bf16 (128^2 structure)
  {
    GemmPs e{};
    e.Bm[0] = WaB; e.bias[0] = ba; e.hidden = hidden; e.haB_out = haB;
    gemm_bt<1><<<dim3(64, 8, 1), dim3(256), 0, stream>>>(hiddenB, hiddenB, 1024, 1024, e);
  }
  // GEMM 2/3: z=0 reset -> rha bf16; z=1 update f32. A = [x | ha] (128^2 structure)
  {
    GemmPs e{};
    e.Bm[0] = WrB; e.Bm[1] = WuB; e.bias[0] = br; e.bias[1] = bu;
    e.haB = haB; e.rhaB = rhaB; e.out_f1 = update;
    gemm_bt<2><<<dim3(64, 8, 2), dim3(256), 0, stream>>>(xB, haB, 1024, 2048, e);
  }
  // GEMM 4: new -> hidden_new (f32 + bf16). A = [x | rha] (128^2 structure)
  {
    GemmPs e{};
    e.Bm[0] = WnB; e.bias[0] = bn; e.hidden = hidden; e.update = update; e.cs = cs;
    e.hn_f32 = hnf; e.hn_bf16 = hiddenB;
    gemm_bt<3><<<dim3(64, 8, 1), dim3(256), 0, stream>>>(xB, rhaB, 1024, 2048, e);
  }
  k_rowmean<<<dim3(2048), dim3(256), 0, stream>>>(hnf, hp);
  // GEMMs 5-8: gate logits — 8-wave 256^2 pipelined kernel (spread staging)
  {
    GemmPs e{};
    e.Bm[0] = WadB; e.Bm[1] = WrdB; e.Bm[2] = WwrB; e.Bm[3] = WfgB;
    e.bias[0] = baddr; e.bias[1] = bread; e.bias[2] = bwrite; e.bias[3] = bforget;
    e.out_b[0] = gAd; e.out_b[1] = gRd; e.out_b[2] = gWr; e.out_b[3] = gFg;
    gemm8<4><<<dim3(256, 1, 4), dim3(512), 0, stream>>>(hiddenB, hiddenB, 1024, 1024, e);
  }
  // final fused softmax / gates / outputs
  k_final<<<dim3(B_), dim3(256), 0, stream>>>(gAd, gRd, gWr, gFg, pm, hnf, hp, outH, outM);
}

// Round 5
// 439.255 us; speedup vs baseline: 1.3408x; 1.0223x over previous
//
#include <hip/hip_runtime.h>

typedef unsigned short u16;
typedef short bfrag __attribute__((ext_vector_type(8)));   // 8 x bf16 (4 VGPR)
typedef float f32x4 __attribute__((ext_vector_type(4)));
typedef const __attribute__((address_space(1))) unsigned int* gp1_t;
typedef __attribute__((address_space(3))) unsigned int* lp3_t;

#define B_ 8192
#define H_ 1024
#define P_ 2048

__device__ __forceinline__ u16 f2bf(float f) {
  unsigned u = __builtin_bit_cast(unsigned, f);
  u += 0x7fffu + ((u >> 16) & 1u);
  return (u16)(u >> 16);
}
__device__ __forceinline__ float bf2f(u16 s) {
  return __builtin_bit_cast(float, (unsigned)s << 16);
}
__device__ __forceinline__ float sigm(float v) { return 1.f / (1.f + __expf(-v)); }

// ---------------- elementwise / reduction kernels ----------------

__global__ void k_hidact(const float* __restrict__ hidden, u16* __restrict__ hB,
                         float* __restrict__ act) {
  const int t = threadIdx.x;                 // 256
  const int r0 = blockIdx.x * 16;            // 512 blocks * 16 rows
  float s00 = 0, s01 = 0, s10 = 0, s11 = 0;
  for (int r = 0; r < 16; ++r) {
    const float* q = hidden + (size_t)(r0 + r) * H_;
    u16* o = hB + (size_t)(r0 + r) * H_;
    float2 v0 = *(const float2*)&q[2 * t];
    float2 v1 = *(const float2*)&q[512 + 2 * t];
    s00 += fabsf(v0.x); s01 += fabsf(v0.y);
    s10 += fabsf(v1.x); s11 += fabsf(v1.y);
    ushort2 o0, o1;
    o0.x = f2bf(v0.x); o0.y = f2bf(v0.y);
    o1.x = f2bf(v1.x); o1.y = f2bf(v1.y);
    *(ushort2*)&o[2 * t] = o0;
    *(ushort2*)&o[512 + 2 * t] = o1;
  }
  atomicAdd(&act[2 * t], s00); atomicAdd(&act[2 * t + 1], s01);
  atomicAdd(&act[512 + 2 * t], s10); atomicAdd(&act[512 + 2 * t + 1], s11);
}

__global__ void k_cs(const float* __restrict__ act, const float* __restrict__ strength,
                     const float* __restrict__ decay, const float* __restrict__ hist,
                     float* __restrict__ cs) {
  int h = blockIdx.x * 256 + threadIdx.x;
  float ch = hist[h] * decay[0] + act[h] * (1.f / (float)B_);
  cs[h] = strength[h] * sigm(ch);
}

struct ConvPs {
  const float* s[9];
  u16* d[9];
  int n4[9];
};

__global__ void k_conv9(ConvPs p) {
  const int e = blockIdx.y;
  const int n4 = p.n4[e];
  const float4* s = (const float4*)p.s[e];
  ushort4* d = (ushort4*)p.d[e];
  for (int i = blockIdx.x * 256 + threadIdx.x; i < n4; i += 2048 * 256) {
    float4 v = s[i];
    ushort4 o;
    o.x = f2bf(v.x); o.y = f2bf(v.y); o.z = f2bf(v.z); o.w = f2bf(v.w);
    d[i] = o;
  }
}

__global__ void k_rowmean(const float* __restrict__ hn, float* __restrict__ hp) {
  int row = blockIdx.x * 4 + (threadIdx.x >> 6);
  int lane = threadIdx.x & 63;
  const float4* p4 = (const float4*)(hn + (size_t)row * H_);
  float s = 0.f;
#pragma unroll
  for (int c = 0; c < 4; ++c) {
    float4 v = p4[lane + c * 64];
    s += v.x + v.y + v.z + v.w;
  }
#pragma unroll
  for (int o = 32; o; o >>= 1) s += __shfl_down(s, o);
  if (lane == 0) hp[row] = s * (1.f / (float)H_);
}

// ---------------- GEMM epilogues (vectorized: lane owns 4 consecutive cols) ----------------

struct GemmPs {
  const u16* Bm[4];
  const float* bias[4];
  const float* hidden;   // f32 [B,1024]
  const float* update;   // f32 [B,1024]
  const float* cs;       // [1024]
  const u16* haB;        // bf16 ha (input to EPI2 z=0)
  u16* rhaB;             // bf16 reset*ha  (EPI2 z=0 out)
  float* out_f1;         // update f32     (EPI2 z=1 out)
  float* hn_f32;         // EPI3
  u16* hn_bf16;          // EPI3
  u16* haB_out;          // EPI1
  u16* out_b[4];         // EPI4 gate logits bf16 [B,2048]
};

template <int EPI>
__device__ __forceinline__ void epiV(int row, int col0, f32x4 v, int z, const GemmPs& e) {
  if constexpr (EPI == 1) {            // attention -> ha (bf16)
    float4 bi = *(const float4*)&e.bias[0][col0];
    size_t i = (size_t)row * H_ + col0;
    float4 hd = *(const float4*)&e.hidden[i];
    ushort4 o;
    o.x = f2bf(hd.x * sigm(v[0] + bi.x));
    o.y = f2bf(hd.y * sigm(v[1] + bi.y));
    o.z = f2bf(hd.z * sigm(v[2] + bi.z));
    o.w = f2bf(hd.w * sigm(v[3] + bi.w));
    *(ushort4*)&e.haB_out[i] = o;
  } else if constexpr (EPI == 2) {     // z=0: reset*ha bf16; z=1: update f32
    size_t i = (size_t)row * H_ + col0;
    if (z == 0) {
      float4 bi = *(const float4*)&e.bias[0][col0];
      ushort4 h = *(const ushort4*)&e.haB[i];
      ushort4 o;
      o.x = f2bf((v[0] + bi.x) * bf2f(h.x));
      o.y = f2bf((v[1] + bi.y) * bf2f(h.y));
      o.z = f2bf((v[2] + bi.z) * bf2f(h.z));
      o.w = f2bf((v[3] + bi.w) * bf2f(h.w));
      *(ushort4*)&e.rhaB[i] = o;
    } else {
      float4 bi = *(const float4*)&e.bias[1][col0];
      float4 o;
      o.x = v[0] + bi.x; o.y = v[1] + bi.y; o.z = v[2] + bi.z; o.w = v[3] + bi.w;
      *(float4*)&e.out_f1[i] = o;
    }
  } else if constexpr (EPI == 3) {     // new -> hidden_new
    float4 bi = *(const float4*)&e.bias[0][col0];
    size_t i = (size_t)row * H_ + col0;
    float4 u4 = *(const float4*)&e.update[i];
    float4 hd = *(const float4*)&e.hidden[i];
    float4 c4 = *(const float4*)&e.cs[col0];
    float4 hn;
    hn.x = (1.f - u4.x) * hd.x + u4.x * (v[0] + bi.x) * c4.x;
    hn.y = (1.f - u4.y) * hd.y + u4.y * (v[1] + bi.y) * c4.y;
    hn.z = (1.f - u4.z) * hd.z + u4.z * (v[2] + bi.z) * c4.z;
    hn.w = (1.f - u4.w) * hd.w + u4.w * (v[3] + bi.w) * c4.w;
    *(float4*)&e.hn_f32[i] = hn;
    ushort4 o;
    o.x = f2bf(hn.x); o.y = f2bf(hn.y); o.z = f2bf(hn.z); o.w = f2bf(hn.w);
    *(ushort4*)&e.hn_bf16[i] = o;
  } else {                             // gate logits bf16
    float4 bi = *(const float4*)&e.bias[z][col0];
    ushort4 o;
    o.x = f2bf(v[0] + bi.x); o.y = f2bf(v[1] + bi.y);
    o.z = f2bf(v[2] + bi.z); o.w = f2bf(v[3] + bi.w);
    *(ushort4*)&e.out_b[z][(size_t)row * P_ + col0] = o;
  }
}

// ---------------- gemm_bt: proven 128x128 / BK=64 / 4-wave structure ----------------
// C[M,N] = A[M,K] * B[N,K]^T. Operand-SWAPPED mfma(b,a): lane holds m=r15 (lane&15),
// n = g*4 + reg (4 consecutive cols) -> vector epilogue stores.
// A split in K: cols [0,K0) from A0 (stride K0), [K0,K) from A1 (stride K-K0).
// LDS XOR-swizzle slot^(row&7) via pre-swizzled global source (linear LDS dest).

template <int EPI>
__global__ __launch_bounds__(256, 2) void gemm_bt(const u16* __restrict__ A0,
                                                  const u16* __restrict__ A1,
                                                  int K0, int K, GemmPs e) {
  const int z = blockIdx.z;
  const u16* __restrict__ Bm = e.Bm[z];
  __shared__ u16 As[128 * 64];
  __shared__ u16 Bs[128 * 64];
  const int lane = threadIdx.x & 63;
  const int w = threadIdx.x >> 6;
  const int wr = w >> 1, wc = w & 1;
  const int m0 = blockIdx.x * 128, n0 = blockIdx.y * 128;

  f32x4 acc[4][4] = {};

  const int rA = lane >> 3;
  const int srcSlot8 = ((lane & 7) ^ (rA & 7)) << 3;

  const int g = lane >> 4;
  const int r15 = lane & 15;
  const int rx = lane & 7;

  for (int k0 = 0; k0 < K; k0 += 64) {
    const u16* Ab; int sA, kl;
    if (k0 < K0) { Ab = A0; sA = K0; kl = k0; }
    else         { Ab = A1; sA = K - K0; kl = k0 - K0; }
    const u16* pA = Ab + (size_t)(m0 + w * 32 + rA) * sA + kl + srcSlot8;
    const u16* pB = Bm + (size_t)(n0 + w * 32 + rA) * K + k0 + srcSlot8;
#pragma unroll
    for (int j = 0; j < 4; ++j) {
      __builtin_amdgcn_global_load_lds((gp1_t)(pA + (size_t)j * 8 * sA),
                                       (lp3_t)&As[(w * 32 + j * 8) * 64], 16, 0, 0);
      __builtin_amdgcn_global_load_lds((gp1_t)(pB + (size_t)j * 8 * K),
                                       (lp3_t)&Bs[(w * 32 + j * 8) * 64], 16, 0, 0);
    }
    asm volatile("s_waitcnt vmcnt(0)" ::: "memory");
    __syncthreads();
#pragma unroll
    for (int kk = 0; kk < 64; kk += 32) {
      const int slot = g + (kk >> 3);
      const int cswz = ((slot ^ rx) << 3);
      bfrag af[4], bq[4];
#pragma unroll
      for (int i = 0; i < 4; ++i) {
        af[i] = *(const bfrag*)&As[(wr * 64 + i * 16 + r15) * 64 + cswz];
        bq[i] = *(const bfrag*)&Bs[(wc * 64 + i * 16 + r15) * 64 + cswz];
      }
#pragma unroll
      for (int mi = 0; mi < 4; ++mi)
#pragma unroll
        for (int ni = 0; ni < 4; ++ni)
          acc[mi][ni] = __builtin_amdgcn_mfma_f32_16x16x32_bf16(bq[ni], af[mi], acc[mi][ni], 0, 0, 0);
    }
    __syncthreads();
  }

  // swapped layout: m = r15 + mi*16, n = g*4 + reg + ni*16 (4 consecutive cols per lane)
#pragma unroll
  for (int mi = 0; mi < 4; ++mi)
#pragma unroll
    for (int ni = 0; ni < 4; ++ni)
      epiV<EPI>(m0 + wr * 64 + mi * 16 + r15,
                n0 + wc * 64 + ni * 16 + g * 4, acc[mi][ni], z, e);
}

// ---------------- final: softmax(addr), sigmoids, memory_new, hidden_final ----------------
// single pass: each thread owns 8 consecutive P-columns in registers.

__global__ __launch_bounds__(256) void k_final(
    const u16* __restrict__ aL, const u16* __restrict__ rL,
    const u16* __restrict__ wL, const u16* __restrict__ fL,
    const float* __restrict__ pm, const float* __restrict__ hn,
    const float* __restrict__ hp, float* __restrict__ outH, float* __restrict__ outM) {
  __shared__ float red[8];
  const int row = blockIdx.x, t = threadIdx.x;
  const size_t base = (size_t)row * P_ + t * 8;

  ushort4 a0 = *(const ushort4*)&aL[base];
  ushort4 a1 = *(const ushort4*)&aL[base + 4];
  float av[8] = {bf2f(a0.x), bf2f(a0.y), bf2f(a0.z), bf2f(a0.w),
                 bf2f(a1.x), bf2f(a1.y), bf2f(a1.z), bf2f(a1.w)};
  float lm = av[0];
#pragma unroll
  for (int j = 1; j < 8; ++j) lm = fmaxf(lm, av[j]);
#pragma unroll
  for (int o = 32; o; o >>= 1) lm = fmaxf(lm, __shfl_xor(lm, o));
  if ((t & 63) == 0) red[t >> 6] = lm;
  __syncthreads();
  const float bmax = fmaxf(fmaxf(red[0], red[1]), fmaxf(red[2], red[3]));

  float ev[8];
  float ls = 0.f;
#pragma unroll
  for (int j = 0; j < 8; ++j) { ev[j] = __expf(av[j] - bmax); ls += ev[j]; }
#pragma unroll
  for (int o = 32; o; o >>= 1) ls += __shfl_xor(ls, o);
  if ((t & 63) == 0) red[4 + (t >> 6)] = ls;
  __syncthreads();
  const float inv = 1.f / (red[4] + red[5] + red[6] + red[7]);
  const float hpv = hp[row];

  ushort4 r0 = *(const ushort4*)&rL[base], r1 = *(const ushort4*)&rL[base + 4];
  ushort4 w0 = *(const ushort4*)&wL[base], w1 = *(const ushort4*)&wL[base + 4];
  ushort4 f0 = *(const ushort4*)&fL[base], f1 = *(const ushort4*)&fL[base + 4];
  float4 p0 = *(const float4*)&pm[base], p1 = *(const float4*)&pm[base + 4];
  float rv[8] = {bf2f(r0.x), bf2f(r0.y), bf2f(r0.z), bf2f(r0.w),
                 bf2f(r1.x), bf2f(r1.y), bf2f(r1.z), bf2f(r1.w)};
  float wv[8] = {bf2f(w0.x), bf2f(w0.y), bf2f(w0.z), bf2f(w0.w),
                 bf2f(w1.x), bf2f(w1.y), bf2f(w1.z), bf2f(w1.w)};
  float fv[8] = {bf2f(f0.x), bf2f(f0.y), bf2f(f0.z), bf2f(f0.w),
                 bf2f(f1.x), bf2f(f1.y), bf2f(f1.z), bf2f(f1.w)};
  float pv[8] = {p0.x, p0.y, p0.z, p0.w, p1.x, p1.y, p1.z, p1.w};
  float mem[8];
  float rs = 0.f;
#pragma unroll
  for (int j = 0; j < 8; ++j) {
    mem[j] = sigm(fv[j]) * pv[j] + sigm(wv[j]) * hpv * (ev[j] * inv);
    rs += sigm(rv[j]) * mem[j];
  }
  float4 m0v = {mem[0], mem[1], mem[2], mem[3]};
  float4 m1v = {mem[4], mem[5], mem[6], mem[7]};
  *(float4*)&outM[base] = m0v;
  *(float4*)&outM[base + 4] = m1v;
#pragma unroll
  for (int o = 32; o; o >>= 1) rs += __shfl_xor(rs, o);
  __syncthreads();
  if ((t & 63) == 0) red[t >> 6] = rs;
  __syncthreads();
  const float mean = (red[0] + red[1] + red[2] + red[3]) * (1.f / (float)P_);
  const size_t hb = (size_t)row * H_ + t * 4;
  float4 h4 = *(const float4*)&hn[hb];
  h4.x += mean; h4.y += mean; h4.z += mean; h4.w += mean;
  *(float4*)&outH[hb] = h4;
}

// ---------------- host ----------------

extern "C" void kernel_launch(void* const* d_in, const int* in_sizes, int n_in,
                              void* d_out, int out_size, void* d_ws, size_t ws_size,
                              hipStream_t stream) {
  (void)in_sizes; (void)n_in; (void)out_size; (void)ws_size;
  const float* x       = (const float*)d_in[0];
  const float* hidden  = (const float*)d_in[1];
  const float* pm      = (const float*)d_in[2];
  const float* Wa      = (const float*)d_in[3];
  const float* ba      = (const float*)d_in[4];
  const float* Wr      = (const float*)d_in[5];
  const float* br      = (const float*)d_in[6];
  const float* Wu      = (const float*)d_in[7];
  const float* bu      = (const float*)d_in[8];
  const float* Wn      = (const float*)d_in[9];
  const float* bn      = (const float*)d_in[10];
  const float* Wread   = (const float*)d_in[11];
  const float* bread   = (const float*)d_in[12];
  const float* Wwrite  = (const float*)d_in[13];
  const float* bwrite  = (const float*)d_in[14];
  const float* Wforget = (const float*)d_in[15];
  const float* bforget = (const float*)d_in[16];
  const float* Waddr   = (const float*)d_in[17];
  const float* baddr   = (const float*)d_in[18];
  const float* cstr    = (const float*)d_in[19];
  const float* cdecay  = (const float*)d_in[20];
  const float* chist   = (const float*)d_in[21];

  char* wsp = (char*)d_ws;
  auto take = [&](size_t n) { char* p = wsp; wsp += (n + 255) & ~(size_t)255; return p; };
  float* act    = (float*)take((size_t)H_ * 4);
  float* cs     = (float*)take((size_t)H_ * 4);
  float* hp     = (float*)take((size_t)B_ * 4);
  u16* hiddenB  = (u16*)take((size_t)B_ * H_ * 2);      // later reused as hidden_new bf16
  u16* xB       = (u16*)take((size_t)B_ * H_ * 2);
  u16* haB      = (u16*)take((size_t)B_ * H_ * 2);
  u16* rhaB     = (u16*)take((size_t)B_ * H_ * 2);
  u16* WaB      = (u16*)take((size_t)H_ * H_ * 2);
  u16* WrB      = (u16*)take((size_t)H_ * 2048 * 2);
  u16* WuB      = (u16*)take((size_t)H_ * 2048 * 2);
  u16* WnB      = (u16*)take((size_t)H_ * 2048 * 2);
  u16* WadB     = (u16*)take((size_t)P_ * H_ * 2);
  u16* WrdB     = (u16*)take((size_t)P_ * H_ * 2);
  u16* WwrB     = (u16*)take((size_t)P_ * H_ * 2);
  u16* WfgB     = (u16*)take((size_t)P_ * H_ * 2);
  float* update = (float*)take((size_t)B_ * H_ * 4);
  float* hnf    = (float*)take((size_t)B_ * H_ * 4);
  u16* gAd      = (u16*)take((size_t)B_ * P_ * 2);
  u16* gRd      = (u16*)take((size_t)B_ * P_ * 2);
  u16* gWr      = (u16*)take((size_t)B_ * P_ * 2);
  u16* gFg      = (u16*)take((size_t)B_ * P_ * 2);

  float* outH = (float*)d_out;
  float* outM = outH + (size_t)B_ * H_;

  // connection strength (fused hidden->bf16 + column |h| sums)
  hipMemsetAsync(act, 0, (size_t)H_ * 4, stream);
  k_hidact<<<dim3(512), dim3(256), 0, stream>>>(hidden, hiddenB, act);
  k_cs<<<dim3(4), dim3(256), 0, stream>>>(act, cstr, cdecay, chist, cs);

  // all conversions in one launch
  {
    ConvPs p;
    const float* ss[9] = {Wa, Wr, Wu, Wn, Waddr, Wread, Wwrite, Wforget, x};
    u16* dd[9] = {WaB, WrB, WuB, WnB, WadB, WrdB, WwrB, WfgB, xB};
    int nn[9] = {H_ * H_ / 4, H_ * 2048 / 4, H_ * 2048 / 4, H_ * 2048 / 4,
                 P_ * H_ / 4, P_ * H_ / 4, P_ * H_ / 4, P_ * H_ / 4, B_ * H_ / 4};
    for (int i = 0; i < 9; ++i) { p.s[i] = ss[i]; p.d[i] = dd[i]; p.n4[i] = nn[i]; }
    k_conv9<<<dim3(2048, 9), dim3(256), 0, stream>>>(p);
  }

  // GEMM 1: attention -> ha bf16
  {
    GemmPs e{};
    e.Bm[0] = WaB; e.bias[0] = ba; e.hidden = hidden; e.haB_out = haB;
    gemm_bt<1><<<dim3(64, 8, 1), dim3(256), 0, stream>>>(hiddenB, hiddenB, 1024, 1024, e);
  }
  // GEMM 2/3: z=0 reset -> rha bf16; z=1 update f32. A = [x | ha]
  {
    GemmPs e{};
    e.Bm[0] = WrB; e.Bm[1] = WuB; e.bias[0] = br; e.bias[1] = bu;
    e.haB = haB; e.rhaB = rhaB; e.out_f1 = update;
    gemm_bt<2><<<dim3(64, 8, 2), dim3(256), 0, stream>>>(xB, haB, 1024, 2048, e);
  }
  // GEMM 4: new -> hidden_new (f32 + bf16). A = [x | rha]
  {
    GemmPs e{};
    e.Bm[0] = WnB; e.bias[0] = bn; e.hidden = hidden; e.update = update; e.cs = cs;
    e.hn_f32 = hnf; e.hn_bf16 = hiddenB;
    gemm_bt<3><<<dim3(64, 8, 1), dim3(256), 0, stream>>>(xB, rhaB, 1024, 2048, e);
  }
  k_rowmean<<<dim3(2048), dim3(256), 0, stream>>>(hnf, hp);
  // GEMMs 5-8: gate logits (addr, read, write, forget) — proven 128^2 structure
  {
    GemmPs e{};
    e.Bm[0] = WadB; e.Bm[1] = WrdB; e.Bm[2] = WwrB; e.Bm[3] = WfgB;
    e.bias[0] = baddr; e.bias[1] = bread; e.bias[2] = bwrite; e.bias[3] = bforget;
    e.out_b[0] = gAd; e.out_b[1] = gRd; e.out_b[2] = gWr; e.out_b[3] = gFg;
    gemm_bt<4><<<dim3(64, 16, 4), dim3(256), 0, stream>>>(hiddenB, hiddenB, 1024, 1024, e);
  }
  // final fused softmax / gates / outputs
  k_final<<<dim3(B_), dim3(256), 0, stream>>>(gAd, gRd, gWr, gFg, pm, hnf, hp, outH, outM);
}

// Round 6
// 432.055 us; speedup vs baseline: 1.3631x; 1.0167x over previous
//
#include <hip/hip_runtime.h>

typedef unsigned short u16;
typedef short bfrag __attribute__((ext_vector_type(8)));   // 8 x bf16 (4 VGPR)
typedef float f32x4 __attribute__((ext_vector_type(4)));
typedef const __attribute__((address_space(1))) unsigned int* gp1_t;
typedef __attribute__((address_space(3))) unsigned int* lp3_t;

#define B_ 8192
#define H_ 1024
#define P_ 2048

__device__ __forceinline__ u16 f2bf(float f) {
  unsigned u = __builtin_bit_cast(unsigned, f);
  u += 0x7fffu + ((u >> 16) & 1u);
  return (u16)(u >> 16);
}
__device__ __forceinline__ float bf2f(u16 s) {
  return __builtin_bit_cast(float, (unsigned)s << 16);
}
__device__ __forceinline__ float sigm(float v) { return 1.f / (1.f + __expf(-v)); }

// ---------------- elementwise / reduction kernels ----------------

__global__ void k_hidact(const float* __restrict__ hidden, u16* __restrict__ hB,
                         float* __restrict__ act) {
  const int t = threadIdx.x;                 // 256
  const int r0 = blockIdx.x * 16;            // 512 blocks * 16 rows
  float s00 = 0, s01 = 0, s10 = 0, s11 = 0;
  for (int r = 0; r < 16; ++r) {
    const float* q = hidden + (size_t)(r0 + r) * H_;
    u16* o = hB + (size_t)(r0 + r) * H_;
    float2 v0 = *(const float2*)&q[2 * t];
    float2 v1 = *(const float2*)&q[512 + 2 * t];
    s00 += fabsf(v0.x); s01 += fabsf(v0.y);
    s10 += fabsf(v1.x); s11 += fabsf(v1.y);
    ushort2 o0, o1;
    o0.x = f2bf(v0.x); o0.y = f2bf(v0.y);
    o1.x = f2bf(v1.x); o1.y = f2bf(v1.y);
    *(ushort2*)&o[2 * t] = o0;
    *(ushort2*)&o[512 + 2 * t] = o1;
  }
  atomicAdd(&act[2 * t], s00); atomicAdd(&act[2 * t + 1], s01);
  atomicAdd(&act[512 + 2 * t], s10); atomicAdd(&act[512 + 2 * t + 1], s11);
}

__global__ void k_cs(const float* __restrict__ act, const float* __restrict__ strength,
                     const float* __restrict__ decay, const float* __restrict__ hist,
                     float* __restrict__ cs) {
  int h = blockIdx.x * 256 + threadIdx.x;
  float ch = hist[h] * decay[0] + act[h] * (1.f / (float)B_);
  cs[h] = strength[h] * sigm(ch);
}

struct ConvPs {
  const float* s[9];
  u16* d[9];
  int n4[9];
};

__global__ void k_conv9(ConvPs p) {
  const int e = blockIdx.y;
  const int n4 = p.n4[e];
  const float4* s = (const float4*)p.s[e];
  ushort4* d = (ushort4*)p.d[e];
  for (int i = blockIdx.x * 256 + threadIdx.x; i < n4; i += 2048 * 256) {
    float4 v = s[i];
    ushort4 o;
    o.x = f2bf(v.x); o.y = f2bf(v.y); o.z = f2bf(v.z); o.w = f2bf(v.w);
    d[i] = o;
  }
}

__global__ void k_rowmean(const float* __restrict__ hn, float* __restrict__ hp) {
  int row = blockIdx.x * 4 + (threadIdx.x >> 6);
  int lane = threadIdx.x & 63;
  const float4* p4 = (const float4*)(hn + (size_t)row * H_);
  float s = 0.f;
#pragma unroll
  for (int c = 0; c < 4; ++c) {
    float4 v = p4[lane + c * 64];
    s += v.x + v.y + v.z + v.w;
  }
#pragma unroll
  for (int o = 32; o; o >>= 1) s += __shfl_down(s, o);
  if (lane == 0) hp[row] = s * (1.f / (float)H_);
}

// ---------------- GEMM epilogues (vectorized: lane owns 4 consecutive cols) ----------------

struct GemmPs {
  const u16* Bm[4];
  const float* bias[4];
  const float* hidden;   // f32 [B,1024]
  const float* update;   // f32 [B,1024]
  const float* cs;       // [1024]
  const u16* haB;        // bf16 ha (input to EPI2 z=0)
  u16* rhaB;             // bf16 reset*ha  (EPI2 z=0 out)
  float* out_f1;         // update f32     (EPI2 z=1 out)
  float* hn_f32;         // EPI3
  u16* hn_bf16;          // EPI3
  u16* haB_out;          // EPI1
  u16* out_b[4];         // EPI4 gate logits bf16 [B,2048]
};

template <int EPI>
__device__ __forceinline__ void epiV(int row, int col0, f32x4 v, int z, const GemmPs& e) {
  if constexpr (EPI == 1) {            // attention -> ha (bf16)
    float4 bi = *(const float4*)&e.bias[0][col0];
    size_t i = (size_t)row * H_ + col0;
    float4 hd = *(const float4*)&e.hidden[i];
    ushort4 o;
    o.x = f2bf(hd.x * sigm(v[0] + bi.x));
    o.y = f2bf(hd.y * sigm(v[1] + bi.y));
    o.z = f2bf(hd.z * sigm(v[2] + bi.z));
    o.w = f2bf(hd.w * sigm(v[3] + bi.w));
    *(ushort4*)&e.haB_out[i] = o;
  } else if constexpr (EPI == 2) {     // z=0: reset*ha bf16; z=1: update f32
    size_t i = (size_t)row * H_ + col0;
    if (z == 0) {
      float4 bi = *(const float4*)&e.bias[0][col0];
      ushort4 h = *(const ushort4*)&e.haB[i];
      ushort4 o;
      o.x = f2bf((v[0] + bi.x) * bf2f(h.x));
      o.y = f2bf((v[1] + bi.y) * bf2f(h.y));
      o.z = f2bf((v[2] + bi.z) * bf2f(h.z));
      o.w = f2bf((v[3] + bi.w) * bf2f(h.w));
      *(ushort4*)&e.rhaB[i] = o;
    } else {
      float4 bi = *(const float4*)&e.bias[1][col0];
      float4 o;
      o.x = v[0] + bi.x; o.y = v[1] + bi.y; o.z = v[2] + bi.z; o.w = v[3] + bi.w;
      *(float4*)&e.out_f1[i] = o;
    }
  } else if constexpr (EPI == 3) {     // new -> hidden_new
    float4 bi = *(const float4*)&e.bias[0][col0];
    size_t i = (size_t)row * H_ + col0;
    float4 u4 = *(const float4*)&e.update[i];
    float4 hd = *(const float4*)&e.hidden[i];
    float4 c4 = *(const float4*)&e.cs[col0];
    float4 hn;
    hn.x = (1.f - u4.x) * hd.x + u4.x * (v[0] + bi.x) * c4.x;
    hn.y = (1.f - u4.y) * hd.y + u4.y * (v[1] + bi.y) * c4.y;
    hn.z = (1.f - u4.z) * hd.z + u4.z * (v[2] + bi.z) * c4.z;
    hn.w = (1.f - u4.w) * hd.w + u4.w * (v[3] + bi.w) * c4.w;
    *(float4*)&e.hn_f32[i] = hn;
    ushort4 o;
    o.x = f2bf(hn.x); o.y = f2bf(hn.y); o.z = f2bf(hn.z); o.w = f2bf(hn.w);
    *(ushort4*)&e.hn_bf16[i] = o;
  } else {                             // gate logits bf16
    float4 bi = *(const float4*)&e.bias[z][col0];
    ushort4 o;
    o.x = f2bf(v[0] + bi.x); o.y = f2bf(v[1] + bi.y);
    o.z = f2bf(v[2] + bi.z); o.w = f2bf(v[3] + bi.w);
    *(ushort4*)&e.out_b[z][(size_t)row * P_ + col0] = o;
  }
}

// ---------------- gemm_bt: proven 128x128 / BK=64 / 4-wave structure ----------------
// C[M,N] = A[M,K] * B[N,K]^T, K = (NT0+NT1)*64. All A buffers have row stride H_=1024
// (compile-time); B row stride KB (compile-time). A split across two buffers realized
// as two sequential K-loops — zero per-iteration stride selection.
// Operand-SWAPPED mfma(b,a): lane holds m=r15, n = g*4+reg -> vector epilogue stores.
// LDS XOR-swizzle slot^(row&7) via pre-swizzled global source (linear LDS dest).

template <int EPI, int KB, int NT0, int NT1>
__global__ __launch_bounds__(256, 2) void gemm_bt(const u16* __restrict__ A0,
                                                  const u16* __restrict__ A1,
                                                  GemmPs e) {
  const int z = blockIdx.z;
  const u16* __restrict__ Bm = e.Bm[z];
  __shared__ u16 As[128 * 64];
  __shared__ u16 Bs[128 * 64];
  const int lane = threadIdx.x & 63;
  const int w = threadIdx.x >> 6;
  const int wr = w >> 1, wc = w & 1;
  const int m0 = blockIdx.x * 128, n0 = blockIdx.y * 128;

  f32x4 acc[4][4] = {};

  const int rA = lane >> 3;
  const int srcSlot8 = ((lane & 7) ^ (rA & 7)) << 3;
  const int g = lane >> 4;
  const int r15 = lane & 15;
  const int rx = lane & 7;

  const u16* pA0 = A0 + (size_t)(m0 + w * 32 + rA) * H_ + srcSlot8;
  const u16* pA1 = A1 + (size_t)(m0 + w * 32 + rA) * H_ + srcSlot8;
  const u16* pB  = Bm + (size_t)(n0 + w * 32 + rA) * KB + srcSlot8;

  auto ktile = [&](const u16* pAk, const u16* pBk) {
#pragma unroll
    for (int j = 0; j < 4; ++j) {
      __builtin_amdgcn_global_load_lds((gp1_t)(pAk + (size_t)(j * 8) * H_),
                                       (lp3_t)&As[(w * 32 + j * 8) * 64], 16, 0, 0);
      __builtin_amdgcn_global_load_lds((gp1_t)(pBk + (size_t)(j * 8) * KB),
                                       (lp3_t)&Bs[(w * 32 + j * 8) * 64], 16, 0, 0);
    }
    asm volatile("s_waitcnt vmcnt(0)" ::: "memory");
    __syncthreads();
#pragma unroll
    for (int kk = 0; kk < 2; ++kk) {
      const int cswz = (((g + kk * 4) ^ rx) << 3);
      bfrag af[4], bq[4];
#pragma unroll
      for (int i = 0; i < 4; ++i) {
        af[i] = *(const bfrag*)&As[(wr * 64 + i * 16 + r15) * 64 + cswz];
        bq[i] = *(const bfrag*)&Bs[(wc * 64 + i * 16 + r15) * 64 + cswz];
      }
#pragma unroll
      for (int mi = 0; mi < 4; ++mi)
#pragma unroll
        for (int ni = 0; ni < 4; ++ni)
          acc[mi][ni] = __builtin_amdgcn_mfma_f32_16x16x32_bf16(bq[ni], af[mi], acc[mi][ni], 0, 0, 0);
    }
    __syncthreads();
  };

  for (int t = 0; t < NT0; ++t) ktile(pA0 + t * 64, pB + t * 64);
  if constexpr (NT1 > 0)
    for (int t = 0; t < NT1; ++t) ktile(pA1 + t * 64, pB + (NT0 + t) * 64);

  // swapped layout: m = r15 + mi*16, n = g*4 + reg + ni*16 (4 consecutive cols per lane)
#pragma unroll
  for (int mi = 0; mi < 4; ++mi)
#pragma unroll
    for (int ni = 0; ni < 4; ++ni)
      epiV<EPI>(m0 + wr * 64 + mi * 16 + r15,
                n0 + wc * 64 + ni * 16 + g * 4, acc[mi][ni], z, e);
}

// ---------------- final: softmax(addr), sigmoids, memory_new, hidden_final ----------------
// single pass: each thread owns 8 consecutive P-columns in registers.

__global__ __launch_bounds__(256) void k_final(
    const u16* __restrict__ aL, const u16* __restrict__ rL,
    const u16* __restrict__ wL, const u16* __restrict__ fL,
    const float* __restrict__ pm, const float* __restrict__ hn,
    const float* __restrict__ hp, float* __restrict__ outH, float* __restrict__ outM) {
  __shared__ float red[8];
  const int row = blockIdx.x, t = threadIdx.x;
  const size_t base = (size_t)row * P_ + t * 8;

  ushort4 a0 = *(const ushort4*)&aL[base];
  ushort4 a1 = *(const ushort4*)&aL[base + 4];
  float av[8] = {bf2f(a0.x), bf2f(a0.y), bf2f(a0.z), bf2f(a0.w),
                 bf2f(a1.x), bf2f(a1.y), bf2f(a1.z), bf2f(a1.w)};
  float lm = av[0];
#pragma unroll
  for (int j = 1; j < 8; ++j) lm = fmaxf(lm, av[j]);
#pragma unroll
  for (int o = 32; o; o >>= 1) lm = fmaxf(lm, __shfl_xor(lm, o));
  if ((t & 63) == 0) red[t >> 6] = lm;
  __syncthreads();
  const float bmax = fmaxf(fmaxf(red[0], red[1]), fmaxf(red[2], red[3]));

  float ev[8];
  float ls = 0.f;
#pragma unroll
  for (int j = 0; j < 8; ++j) { ev[j] = __expf(av[j] - bmax); ls += ev[j]; }
#pragma unroll
  for (int o = 32; o; o >>= 1) ls += __shfl_xor(ls, o);
  if ((t & 63) == 0) red[4 + (t >> 6)] = ls;
  __syncthreads();
  const float inv = 1.f / (red[4] + red[5] + red[6] + red[7]);
  const float hpv = hp[row];

  ushort4 r0 = *(const ushort4*)&rL[base], r1 = *(const ushort4*)&rL[base + 4];
  ushort4 w0 = *(const ushort4*)&wL[base], w1 = *(const ushort4*)&wL[base + 4];
  ushort4 f0 = *(const ushort4*)&fL[base], f1 = *(const ushort4*)&fL[base + 4];
  float4 p0 = *(const float4*)&pm[base], p1 = *(const float4*)&pm[base + 4];
  float rv[8] = {bf2f(r0.x), bf2f(r0.y), bf2f(r0.z), bf2f(r0.w),
                 bf2f(r1.x), bf2f(r1.y), bf2f(r1.z), bf2f(r1.w)};
  float wv[8] = {bf2f(w0.x), bf2f(w0.y), bf2f(w0.z), bf2f(w0.w),
                 bf2f(w1.x), bf2f(w1.y), bf2f(w1.z), bf2f(w1.w)};
  float fv[8] = {bf2f(f0.x), bf2f(f0.y), bf2f(f0.z), bf2f(f0.w),
                 bf2f(f1.x), bf2f(f1.y), bf2f(f1.z), bf2f(f1.w)};
  float pv[8] = {p0.x, p0.y, p0.z, p0.w, p1.x, p1.y, p1.z, p1.w};
  float mem[8];
  float rs = 0.f;
#pragma unroll
  for (int j = 0; j < 8; ++j) {
    mem[j] = sigm(fv[j]) * pv[j] + sigm(wv[j]) * hpv * (ev[j] * inv);
    rs += sigm(rv[j]) * mem[j];
  }
  float4 m0v = {mem[0], mem[1], mem[2], mem[3]};
  float4 m1v = {mem[4], mem[5], mem[6], mem[7]};
  *(float4*)&outM[base] = m0v;
  *(float4*)&outM[base + 4] = m1v;
#pragma unroll
  for (int o = 32; o; o >>= 1) rs += __shfl_xor(rs, o);
  __syncthreads();
  if ((t & 63) == 0) red[t >> 6] = rs;
  __syncthreads();
  const float mean = (red[0] + red[1] + red[2] + red[3]) * (1.f / (float)P_);
  const size_t hb = (size_t)row * H_ + t * 4;
  float4 h4 = *(const float4*)&hn[hb];
  h4.x += mean; h4.y += mean; h4.z += mean; h4.w += mean;
  *(float4*)&outH[hb] = h4;
}

// ---------------- host ----------------

extern "C" void kernel_launch(void* const* d_in, const int* in_sizes, int n_in,
                              void* d_out, int out_size, void* d_ws, size_t ws_size,
                              hipStream_t stream) {
  (void)in_sizes; (void)n_in; (void)out_size; (void)ws_size;
  const float* x       = (const float*)d_in[0];
  const float* hidden  = (const float*)d_in[1];
  const float* pm      = (const float*)d_in[2];
  const float* Wa      = (const float*)d_in[3];
  const float* ba      = (const float*)d_in[4];
  const float* Wr      = (const float*)d_in[5];
  const float* br      = (const float*)d_in[6];
  const float* Wu      = (const float*)d_in[7];
  const float* bu      = (const float*)d_in[8];
  const float* Wn      = (const float*)d_in[9];
  const float* bn      = (const float*)d_in[10];
  const float* Wread   = (const float*)d_in[11];
  const float* bread   = (const float*)d_in[12];
  const float* Wwrite  = (const float*)d_in[13];
  const float* bwrite  = (const float*)d_in[14];
  const float* Wforget = (const float*)d_in[15];
  const float* bforget = (const float*)d_in[16];
  const float* Waddr   = (const float*)d_in[17];
  const float* baddr   = (const float*)d_in[18];
  const float* cstr    = (const float*)d_in[19];
  const float* cdecay  = (const float*)d_in[20];
  const float* chist   = (const float*)d_in[21];

  char* wsp = (char*)d_ws;
  auto take = [&](size_t n) { char* p = wsp; wsp += (n + 255) & ~(size_t)255; return p; };
  float* act    = (float*)take((size_t)H_ * 4);
  float* cs     = (float*)take((size_t)H_ * 4);
  float* hp     = (float*)take((size_t)B_ * 4);
  u16* hiddenB  = (u16*)take((size_t)B_ * H_ * 2);      // later reused as hidden_new bf16
  u16* xB       = (u16*)take((size_t)B_ * H_ * 2);
  u16* haB      = (u16*)take((size_t)B_ * H_ * 2);
  u16* rhaB     = (u16*)take((size_t)B_ * H_ * 2);
  u16* WaB      = (u16*)take((size_t)H_ * H_ * 2);
  u16* WrB      = (u16*)take((size_t)H_ * 2048 * 2);
  u16* WuB      = (u16*)take((size_t)H_ * 2048 * 2);
  u16* WnB      = (u16*)take((size_t)H_ * 2048 * 2);
  u16* WadB     = (u16*)take((size_t)P_ * H_ * 2);
  u16* WrdB     = (u16*)take((size_t)P_ * H_ * 2);
  u16* WwrB     = (u16*)take((size_t)P_ * H_ * 2);
  u16* WfgB     = (u16*)take((size_t)P_ * H_ * 2);
  float* update = (float*)take((size_t)B_ * H_ * 4);
  float* hnf    = (float*)take((size_t)B_ * H_ * 4);
  u16* gAd      = (u16*)take((size_t)B_ * P_ * 2);
  u16* gRd      = (u16*)take((size_t)B_ * P_ * 2);
  u16* gWr      = (u16*)take((size_t)B_ * P_ * 2);
  u16* gFg      = (u16*)take((size_t)B_ * P_ * 2);

  float* outH = (float*)d_out;
  float* outM = outH + (size_t)B_ * H_;

  // connection strength (fused hidden->bf16 + column |h| sums)
  hipMemsetAsync(act, 0, (size_t)H_ * 4, stream);
  k_hidact<<<dim3(512), dim3(256), 0, stream>>>(hidden, hiddenB, act);
  k_cs<<<dim3(4), dim3(256), 0, stream>>>(act, cstr, cdecay, chist, cs);

  // all conversions in one launch
  {
    ConvPs p;
    const float* ss[9] = {Wa, Wr, Wu, Wn, Waddr, Wread, Wwrite, Wforget, x};
    u16* dd[9] = {WaB, WrB, WuB, WnB, WadB, WrdB, WwrB, WfgB, xB};
    int nn[9] = {H_ * H_ / 4, H_ * 2048 / 4, H_ * 2048 / 4, H_ * 2048 / 4,
                 P_ * H_ / 4, P_ * H_ / 4, P_ * H_ / 4, P_ * H_ / 4, B_ * H_ / 4};
    for (int i = 0; i < 9; ++i) { p.s[i] = ss[i]; p.d[i] = dd[i]; p.n4[i] = nn[i]; }
    k_conv9<<<dim3(2048, 9), dim3(256), 0, stream>>>(p);
  }

  // GEMM 1: attention -> ha bf16
  {
    GemmPs e{};
    e.Bm[0] = WaB; e.bias[0] = ba; e.hidden = hidden; e.haB_out = haB;
    gemm_bt<1, 1024, 16, 0><<<dim3(64, 8, 1), dim3(256), 0, stream>>>(hiddenB, hiddenB, e);
  }
  // GEMM 2/3: z=0 reset -> rha bf16; z=1 update f32. A = [x | ha]
  {
    GemmPs e{};
    e.Bm[0] = WrB; e.Bm[1] = WuB; e.bias[0] = br; e.bias[1] = bu;
    e.haB = haB; e.rhaB = rhaB; e.out_f1 = update;
    gemm_bt<2, 2048, 16, 16><<<dim3(64, 8, 2), dim3(256), 0, stream>>>(xB, haB, e);
  }
  // GEMM 4: new -> hidden_new (f32 + bf16). A = [x | rha]
  {
    GemmPs e{};
    e.Bm[0] = WnB; e.bias[0] = bn; e.hidden = hidden; e.update = update; e.cs = cs;
    e.hn_f32 = hnf; e.hn_bf16 = hiddenB;
    gemm_bt<3, 2048, 16, 16><<<dim3(64, 8, 1), dim3(256), 0, stream>>>(xB, rhaB, e);
  }
  k_rowmean<<<dim3(2048), dim3(256), 0, stream>>>(hnf, hp);
  // GEMMs 5-8: gate logits (addr, read, write, forget)
  {
    GemmPs e{};
    e.Bm[0] = WadB; e.Bm[1] = WrdB; e.Bm[2] = WwrB; e.Bm[3] = WfgB;
    e.bias[0] = baddr; e.bias[1] = bread; e.bias[2] = bwrite; e.bias[3] = bforget;
    e.out_b[0] = gAd; e.out_b[1] = gRd; e.out_b[2] = gWr; e.out_b[3] = gFg;
    gemm_bt<4, 1024, 16, 0><<<dim3(64, 16, 4), dim3(256), 0, stream>>>(hiddenB, hiddenB, e);
  }
  // final fused softmax / gates / outputs
  k_final<<<dim3(B_), dim3(256), 0, stream>>>(gAd, gRd, gWr, gFg, pm, hnf, hp, outH, outM);
}

// Round 7
// 403.463 us; speedup vs baseline: 1.4597x; 1.0709x over previous
//
#include <hip/hip_runtime.h>

typedef unsigned short u16;
typedef short bfrag __attribute__((ext_vector_type(8)));   // 8 x bf16 (4 VGPR)
typedef float f32x4 __attribute__((ext_vector_type(4)));
typedef const __attribute__((address_space(1))) unsigned int* gp1_t;
typedef __attribute__((address_space(3))) unsigned int* lp3_t;

#define B_ 8192
#define H_ 1024
#define P_ 2048

__device__ __forceinline__ u16 f2bf(float f) {
  unsigned u = __builtin_bit_cast(unsigned, f);
  u += 0x7fffu + ((u >> 16) & 1u);
  return (u16)(u >> 16);
}
__device__ __forceinline__ float bf2f(u16 s) {
  return __builtin_bit_cast(float, (unsigned)s << 16);
}
__device__ __forceinline__ float sigm(float v) { return 1.f / (1.f + __expf(-v)); }

// ---------------- elementwise / reduction kernels ----------------

// fused hidden f32 -> bf16 + per-column sum|h| (128 blocks x 64 rows, float4 loads)
__global__ void k_hidact(const float* __restrict__ hidden, u16* __restrict__ hB,
                         float* __restrict__ act) {
  const int t = threadIdx.x;                 // 256: col block t*4
  const int r0 = blockIdx.x * 64;
  float s0 = 0, s1 = 0, s2 = 0, s3 = 0;
  for (int r = 0; r < 64; ++r) {
    const size_t i = (size_t)(r0 + r) * H_ + t * 4;
    float4 v = *(const float4*)&hidden[i];
    s0 += fabsf(v.x); s1 += fabsf(v.y); s2 += fabsf(v.z); s3 += fabsf(v.w);
    ushort4 o;
    o.x = f2bf(v.x); o.y = f2bf(v.y); o.z = f2bf(v.z); o.w = f2bf(v.w);
    *(ushort4*)&hB[i] = o;
  }
  atomicAdd(&act[t * 4], s0); atomicAdd(&act[t * 4 + 1], s1);
  atomicAdd(&act[t * 4 + 2], s2); atomicAdd(&act[t * 4 + 3], s3);
}

__global__ void k_cs(const float* __restrict__ act, const float* __restrict__ strength,
                     const float* __restrict__ decay, const float* __restrict__ hist,
                     float* __restrict__ cs) {
  int h = blockIdx.x * 256 + threadIdx.x;
  float ch = hist[h] * decay[0] + act[h] * (1.f / (float)B_);
  cs[h] = strength[h] * sigm(ch);
}

struct ConvPs {
  const float* s[9];
  u16* d[9];
  int n4[9];
};

__global__ void k_conv9(ConvPs p) {
  const int e = blockIdx.y;
  const int n4 = p.n4[e];
  const float4* s = (const float4*)p.s[e];
  ushort4* d = (ushort4*)p.d[e];
  for (int i = blockIdx.x * 256 + threadIdx.x; i < n4; i += 2048 * 256) {
    float4 v = s[i];
    ushort4 o;
    o.x = f2bf(v.x); o.y = f2bf(v.y); o.z = f2bf(v.z); o.w = f2bf(v.w);
    d[i] = o;
  }
}

// ---------------- GEMM epilogues (vectorized: lane owns 4 consecutive cols) ----------------

struct GemmPs {
  const u16* Bm[4];
  const float* bias[4];
  const float* hidden;   // f32 [B,1024]
  const float* update;   // f32 [B,1024]
  const float* cs;       // [1024]
  const u16* haB;        // bf16 ha (input to EPI2 z=0)
  u16* rhaB;             // bf16 reset*ha  (EPI2 z=0 out)
  float* out_f1;         // update f32     (EPI2 z=1 out)
  u16* hn_bf16;          // EPI3
  float* hp;             // EPI3: row-sum of hn (atomicAdd), scaled 1/H at use
  u16* haB_out;          // EPI1
  u16* out_b[4];         // EPI4 gate logits bf16 [B,2048]
};

// returns per-call row-sum contribution (EPI3 only; else 0)
template <int EPI>
__device__ __forceinline__ float epiV(int row, int col0, f32x4 v, int z, const GemmPs& e) {
  if constexpr (EPI == 1) {            // attention -> ha (bf16)
    float4 bi = *(const float4*)&e.bias[0][col0];
    size_t i = (size_t)row * H_ + col0;
    float4 hd = *(const float4*)&e.hidden[i];
    ushort4 o;
    o.x = f2bf(hd.x * sigm(v[0] + bi.x));
    o.y = f2bf(hd.y * sigm(v[1] + bi.y));
    o.z = f2bf(hd.z * sigm(v[2] + bi.z));
    o.w = f2bf(hd.w * sigm(v[3] + bi.w));
    *(ushort4*)&e.haB_out[i] = o;
    return 0.f;
  } else if constexpr (EPI == 2) {     // z=0: reset*ha bf16; z=1: update f32
    size_t i = (size_t)row * H_ + col0;
    if (z == 0) {
      float4 bi = *(const float4*)&e.bias[0][col0];
      ushort4 h = *(const ushort4*)&e.haB[i];
      ushort4 o;
      o.x = f2bf((v[0] + bi.x) * bf2f(h.x));
      o.y = f2bf((v[1] + bi.y) * bf2f(h.y));
      o.z = f2bf((v[2] + bi.z) * bf2f(h.z));
      o.w = f2bf((v[3] + bi.w) * bf2f(h.w));
      *(ushort4*)&e.rhaB[i] = o;
    } else {
      float4 bi = *(const float4*)&e.bias[1][col0];
      float4 o;
      o.x = v[0] + bi.x; o.y = v[1] + bi.y; o.z = v[2] + bi.z; o.w = v[3] + bi.w;
      *(float4*)&e.out_f1[i] = o;
    }
    return 0.f;
  } else if constexpr (EPI == 3) {     // new -> hidden_new (bf16 store + f32 row-sum)
    float4 bi = *(const float4*)&e.bias[0][col0];
    size_t i = (size_t)row * H_ + col0;
    float4 u4 = *(const float4*)&e.update[i];
    float4 hd = *(const float4*)&e.hidden[i];
    float4 c4 = *(const float4*)&e.cs[col0];
    float hx = (1.f - u4.x) * hd.x + u4.x * (v[0] + bi.x) * c4.x;
    float hy = (1.f - u4.y) * hd.y + u4.y * (v[1] + bi.y) * c4.y;
    float hz = (1.f - u4.z) * hd.z + u4.z * (v[2] + bi.z) * c4.z;
    float hw = (1.f - u4.w) * hd.w + u4.w * (v[3] + bi.w) * c4.w;
    ushort4 o;
    o.x = f2bf(hx); o.y = f2bf(hy); o.z = f2bf(hz); o.w = f2bf(hw);
    *(ushort4*)&e.hn_bf16[i] = o;
    return hx + hy + hz + hw;
  } else {                             // gate logits bf16
    float4 bi = *(const float4*)&e.bias[z][col0];
    ushort4 o;
    o.x = f2bf(v[0] + bi.x); o.y = f2bf(v[1] + bi.y);
    o.z = f2bf(v[2] + bi.z); o.w = f2bf(v[3] + bi.w);
    *(ushort4*)&e.out_b[z][(size_t)row * P_ + col0] = o;
    return 0.f;
  }
}

// ---------------- gemm_bt: proven 128x128 / BK=64 / 4-wave structure ----------------
// C[M,N] = A[M,K] * B[N,K]^T, K = (NT0+NT1)*64. A row stride H_ (compile-time);
// B row stride KB (compile-time). A K-split realized as two sequential loops.
// Operand-SWAPPED mfma(b,a): lane holds m=r15, n = g*4+reg -> vector epilogue stores.
// LDS XOR-swizzle slot^(row&7) via pre-swizzled global source (linear LDS dest).

template <int EPI, int KB, int NT0, int NT1>
__global__ __launch_bounds__(256, 2) void gemm_bt(const u16* __restrict__ A0,
                                                  const u16* __restrict__ A1,
                                                  GemmPs e) {
  const int z = blockIdx.z;
  const u16* __restrict__ Bm = e.Bm[z];
  __shared__ u16 As[128 * 64];
  __shared__ u16 Bs[128 * 64];
  const int lane = threadIdx.x & 63;
  const int w = threadIdx.x >> 6;
  const int wr = w >> 1, wc = w & 1;
  const int m0 = blockIdx.x * 128, n0 = blockIdx.y * 128;

  f32x4 acc[4][4] = {};

  const int rA = lane >> 3;
  const int srcSlot8 = ((lane & 7) ^ (rA & 7)) << 3;
  const int g = lane >> 4;
  const int r15 = lane & 15;
  const int rx = lane & 7;

  const u16* pA0 = A0 + (size_t)(m0 + w * 32 + rA) * H_ + srcSlot8;
  const u16* pA1 = A1 + (size_t)(m0 + w * 32 + rA) * H_ + srcSlot8;
  const u16* pB  = Bm + (size_t)(n0 + w * 32 + rA) * KB + srcSlot8;

  auto ktile = [&](const u16* pAk, const u16* pBk) {
#pragma unroll
    for (int j = 0; j < 4; ++j) {
      __builtin_amdgcn_global_load_lds((gp1_t)(pAk + (size_t)(j * 8) * H_),
                                       (lp3_t)&As[(w * 32 + j * 8) * 64], 16, 0, 0);
      __builtin_amdgcn_global_load_lds((gp1_t)(pBk + (size_t)(j * 8) * KB),
                                       (lp3_t)&Bs[(w * 32 + j * 8) * 64], 16, 0, 0);
    }
    asm volatile("s_waitcnt vmcnt(0)" ::: "memory");
    __syncthreads();
#pragma unroll
    for (int kk = 0; kk < 2; ++kk) {
      const int cswz = (((g + kk * 4) ^ rx) << 3);
      bfrag af[4], bq[4];
#pragma unroll
      for (int i = 0; i < 4; ++i) {
        af[i] = *(const bfrag*)&As[(wr * 64 + i * 16 + r15) * 64 + cswz];
        bq[i] = *(const bfrag*)&Bs[(wc * 64 + i * 16 + r15) * 64 + cswz];
      }
#pragma unroll
      for (int mi = 0; mi < 4; ++mi)
#pragma unroll
        for (int ni = 0; ni < 4; ++ni)
          acc[mi][ni] = __builtin_amdgcn_mfma_f32_16x16x32_bf16(bq[ni], af[mi], acc[mi][ni], 0, 0, 0);
    }
    __syncthreads();
  };

  for (int t = 0; t < NT0; ++t) ktile(pA0 + t * 64, pB + t * 64);
  if constexpr (NT1 > 0)
    for (int t = 0; t < NT1; ++t) ktile(pA1 + t * 64, pB + (NT0 + t) * 64);

  // swapped layout: m = r15 + mi*16, n = g*4 + reg + ni*16 (4 consecutive cols per lane)
  if constexpr (EPI == 3) {
    float rsum[4];
#pragma unroll
    for (int mi = 0; mi < 4; ++mi) {
      rsum[mi] = 0.f;
#pragma unroll
      for (int ni = 0; ni < 4; ++ni)
        rsum[mi] += epiV<EPI>(m0 + wr * 64 + mi * 16 + r15,
                              n0 + wc * 64 + ni * 16 + g * 4, acc[mi][ni], z, e);
    }
#pragma unroll
    for (int mi = 0; mi < 4; ++mi) {
      float s = rsum[mi];
      s += __shfl_xor(s, 16);
      s += __shfl_xor(s, 32);
      if (g == 0) atomicAdd(&e.hp[m0 + wr * 64 + mi * 16 + r15], s);
    }
  } else {
#pragma unroll
    for (int mi = 0; mi < 4; ++mi)
#pragma unroll
      for (int ni = 0; ni < 4; ++ni)
        epiV<EPI>(m0 + wr * 64 + mi * 16 + r15,
                  n0 + wc * 64 + ni * 16 + g * 4, acc[mi][ni], z, e);
  }
}

// ---------------- final: softmax(addr), sigmoids, memory_new, hidden_final ----------------
// single pass: each thread owns 8 consecutive P-columns in registers.

__global__ __launch_bounds__(256) void k_final(
    const u16* __restrict__ aL, const u16* __restrict__ rL,
    const u16* __restrict__ wL, const u16* __restrict__ fL,
    const float* __restrict__ pm, const u16* __restrict__ hnB,
    const float* __restrict__ hp, float* __restrict__ outH, float* __restrict__ outM) {
  __shared__ float red[8];
  const int row = blockIdx.x, t = threadIdx.x;
  const size_t base = (size_t)row * P_ + t * 8;

  ushort4 a0 = *(const ushort4*)&aL[base];
  ushort4 a1 = *(const ushort4*)&aL[base + 4];
  float av[8] = {bf2f(a0.x), bf2f(a0.y), bf2f(a0.z), bf2f(a0.w),
                 bf2f(a1.x), bf2f(a1.y), bf2f(a1.z), bf2f(a1.w)};
  float lm = av[0];
#pragma unroll
  for (int j = 1; j < 8; ++j) lm = fmaxf(lm, av[j]);
#pragma unroll
  for (int o = 32; o; o >>= 1) lm = fmaxf(lm, __shfl_xor(lm, o));
  if ((t & 63) == 0) red[t >> 6] = lm;
  __syncthreads();
  const float bmax = fmaxf(fmaxf(red[0], red[1]), fmaxf(red[2], red[3]));

  float ev[8];
  float ls = 0.f;
#pragma unroll
  for (int j = 0; j < 8; ++j) { ev[j] = __expf(av[j] - bmax); ls += ev[j]; }
#pragma unroll
  for (int o = 32; o; o >>= 1) ls += __shfl_xor(ls, o);
  if ((t & 63) == 0) red[4 + (t >> 6)] = ls;
  __syncthreads();
  const float inv = 1.f / (red[4] + red[5] + red[6] + red[7]);
  const float hpv = hp[row] * (1.f / (float)H_);

  ushort4 r0 = *(const ushort4*)&rL[base], r1 = *(const ushort4*)&rL[base + 4];
  ushort4 w0 = *(const ushort4*)&wL[base], w1 = *(const ushort4*)&wL[base + 4];
  ushort4 f0 = *(const ushort4*)&fL[base], f1 = *(const ushort4*)&fL[base + 4];
  float4 p0 = *(const float4*)&pm[base], p1 = *(const float4*)&pm[base + 4];
  float rv[8] = {bf2f(r0.x), bf2f(r0.y), bf2f(r0.z), bf2f(r0.w),
                 bf2f(r1.x), bf2f(r1.y), bf2f(r1.z), bf2f(r1.w)};
  float wv[8] = {bf2f(w0.x), bf2f(w0.y), bf2f(w0.z), bf2f(w0.w),
                 bf2f(w1.x), bf2f(w1.y), bf2f(w1.z), bf2f(w1.w)};
  float fv[8] = {bf2f(f0.x), bf2f(f0.y), bf2f(f0.z), bf2f(f0.w),
                 bf2f(f1.x), bf2f(f1.y), bf2f(f1.z), bf2f(f1.w)};
  float pv[8] = {p0.x, p0.y, p0.z, p0.w, p1.x, p1.y, p1.z, p1.w};
  float mem[8];
  float rs = 0.f;
#pragma unroll
  for (int j = 0; j < 8; ++j) {
    mem[j] = sigm(fv[j]) * pv[j] + sigm(wv[j]) * hpv * (ev[j] * inv);
    rs += sigm(rv[j]) * mem[j];
  }
  float4 m0v = {mem[0], mem[1], mem[2], mem[3]};
  float4 m1v = {mem[4], mem[5], mem[6], mem[7]};
  *(float4*)&outM[base] = m0v;
  *(float4*)&outM[base + 4] = m1v;
#pragma unroll
  for (int o = 32; o; o >>= 1) rs += __shfl_xor(rs, o);
  __syncthreads();
  if ((t & 63) == 0) red[t >> 6] = rs;
  __syncthreads();
  const float mean = (red[0] + red[1] + red[2] + red[3]) * (1.f / (float)P_);
  const size_t hb = (size_t)row * H_ + t * 4;
  ushort4 h4 = *(const ushort4*)&hnB[hb];
  float4 o4;
  o4.x = bf2f(h4.x) + mean; o4.y = bf2f(h4.y) + mean;
  o4.z = bf2f(h4.z) + mean; o4.w = bf2f(h4.w) + mean;
  *(float4*)&outH[hb] = o4;
}

// ---------------- host ----------------

extern "C" void kernel_launch(void* const* d_in, const int* in_sizes, int n_in,
                              void* d_out, int out_size, void* d_ws, size_t ws_size,
                              hipStream_t stream) {
  (void)in_sizes; (void)n_in; (void)out_size; (void)ws_size;
  const float* x       = (const float*)d_in[0];
  const float* hidden  = (const float*)d_in[1];
  const float* pm      = (const float*)d_in[2];
  const float* Wa      = (const float*)d_in[3];
  const float* ba      = (const float*)d_in[4];
  const float* Wr      = (const float*)d_in[5];
  const float* br      = (const float*)d_in[6];
  const float* Wu      = (const float*)d_in[7];
  const float* bu      = (const float*)d_in[8];
  const float* Wn      = (const float*)d_in[9];
  const float* bn      = (const float*)d_in[10];
  const float* Wread   = (const float*)d_in[11];
  const float* bread   = (const float*)d_in[12];
  const float* Wwrite  = (const float*)d_in[13];
  const float* bwrite  = (const float*)d_in[14];
  const float* Wforget = (const float*)d_in[15];
  const float* bforget = (const float*)d_in[16];
  const float* Waddr   = (const float*)d_in[17];
  const float* baddr   = (const float*)d_in[18];
  const float* cstr    = (const float*)d_in[19];
  const float* cdecay  = (const float*)d_in[20];
  const float* chist   = (const float*)d_in[21];

  char* wsp = (char*)d_ws;
  auto take = [&](size_t n) { char* p = wsp; wsp += (n + 255) & ~(size_t)255; return p; };
  float* act    = (float*)take((size_t)H_ * 4);          // zeroed (with hp) each call
  float* hp     = (float*)take((size_t)B_ * 4);          // row-sums of hn (atomic)
  float* cs     = (float*)take((size_t)H_ * 4);
  u16* hiddenB  = (u16*)take((size_t)B_ * H_ * 2);       // later reused as hidden_new bf16
  u16* xB       = (u16*)take((size_t)B_ * H_ * 2);
  u16* haB      = (u16*)take((size_t)B_ * H_ * 2);
  u16* rhaB     = (u16*)take((size_t)B_ * H_ * 2);
  u16* WaB      = (u16*)take((size_t)H_ * H_ * 2);
  u16* WrB      = (u16*)take((size_t)H_ * 2048 * 2);
  u16* WuB      = (u16*)take((size_t)H_ * 2048 * 2);
  u16* WnB      = (u16*)take((size_t)H_ * 2048 * 2);
  u16* WadB     = (u16*)take((size_t)P_ * H_ * 2);
  u16* WrdB     = (u16*)take((size_t)P_ * H_ * 2);
  u16* WwrB     = (u16*)take((size_t)P_ * H_ * 2);
  u16* WfgB     = (u16*)take((size_t)P_ * H_ * 2);
  float* update = (float*)take((size_t)B_ * H_ * 4);
  u16* gAd      = (u16*)take((size_t)B_ * P_ * 2);
  u16* gRd      = (u16*)take((size_t)B_ * P_ * 2);
  u16* gWr      = (u16*)take((size_t)B_ * P_ * 2);
  u16* gFg      = (u16*)take((size_t)B_ * P_ * 2);

  float* outH = (float*)d_out;
  float* outM = outH + (size_t)B_ * H_;

  // zero act + hp (adjacent, single memset)
  hipMemsetAsync(act, 0, (size_t)H_ * 4 + (size_t)B_ * 4, stream);
  // fused hidden->bf16 + column |h| sums
  k_hidact<<<dim3(128), dim3(256), 0, stream>>>(hidden, hiddenB, act);
  k_cs<<<dim3(4), dim3(256), 0, stream>>>(act, cstr, cdecay, chist, cs);

  // all conversions in one launch
  {
    ConvPs p;
    const float* ss[9] = {Wa, Wr, Wu, Wn, Waddr, Wread, Wwrite, Wforget, x};
    u16* dd[9] = {WaB, WrB, WuB, WnB, WadB, WrdB, WwrB, WfgB, xB};
    int nn[9] = {H_ * H_ / 4, H_ * 2048 / 4, H_ * 2048 / 4, H_ * 2048 / 4,
                 P_ * H_ / 4, P_ * H_ / 4, P_ * H_ / 4, P_ * H_ / 4, B_ * H_ / 4};
    for (int i = 0; i < 9; ++i) { p.s[i] = ss[i]; p.d[i] = dd[i]; p.n4[i] = nn[i]; }
    k_conv9<<<dim3(2048, 9), dim3(256), 0, stream>>>(p);
  }

  // GEMM 1: attention -> ha bf16
  {
    GemmPs e{};
    e.Bm[0] = WaB; e.bias[0] = ba; e.hidden = hidden; e.haB_out = haB;
    gemm_bt<1, 1024, 16, 0><<<dim3(64, 8, 1), dim3(256), 0, stream>>>(hiddenB, hiddenB, e);
  }
  // GEMM 2/3: z=0 reset -> rha bf16; z=1 update f32. A = [x | ha]
  {
    GemmPs e{};
    e.Bm[0] = WrB; e.Bm[1] = WuB; e.bias[0] = br; e.bias[1] = bu;
    e.haB = haB; e.rhaB = rhaB; e.out_f1 = update;
    gemm_bt<2, 2048, 16, 16><<<dim3(64, 8, 2), dim3(256), 0, stream>>>(xB, haB, e);
  }
  // GEMM 4: new -> hidden_new bf16 + fused row-sum (hp). A = [x | rha]
  {
    GemmPs e{};
    e.Bm[0] = WnB; e.bias[0] = bn; e.hidden = hidden; e.update = update; e.cs = cs;
    e.hn_bf16 = hiddenB; e.hp = hp;
    gemm_bt<3, 2048, 16, 16><<<dim3(64, 8, 1), dim3(256), 0, stream>>>(xB, rhaB, e);
  }
  // GEMMs 5-8: gate logits (addr, read, write, forget)
  {
    GemmPs e{};
    e.Bm[0] = WadB; e.Bm[1] = WrdB; e.Bm[2] = WwrB; e.Bm[3] = WfgB;
    e.bias[0] = baddr; e.bias[1] = bread; e.bias[2] = bwrite; e.bias[3] = bforget;
    e.out_b[0] = gAd; e.out_b[1] = gRd; e.out_b[2] = gWr; e.out_b[3] = gFg;
    gemm_bt<4, 1024, 16, 0><<<dim3(64, 16, 4), dim3(256), 0, stream>>>(hiddenB, hiddenB, e);
  }
  // final fused softmax / gates / outputs
  k_final<<<dim3(B_), dim3(256), 0, stream>>>(gAd, gRd, gWr, gFg, pm, hiddenB, hp, outH, outM);
}

// Round 8
// 400.830 us; speedup vs baseline: 1.4693x; 1.0066x over previous
//
#include <hip/hip_runtime.h>

typedef unsigned short u16;
typedef short bfrag __attribute__((ext_vector_type(8)));   // 8 x bf16 (4 VGPR)
typedef float f32x4 __attribute__((ext_vector_type(4)));
typedef const __attribute__((address_space(1))) unsigned int* gp1_t;
typedef __attribute__((address_space(3))) unsigned int* lp3_t;

#define B_ 8192
#define H_ 1024
#define P_ 2048

__device__ __forceinline__ u16 f2bf(float f) {
  unsigned u = __builtin_bit_cast(unsigned, f);
  u += 0x7fffu + ((u >> 16) & 1u);
  return (u16)(u >> 16);
}
__device__ __forceinline__ float bf2f(u16 s) {
  return __builtin_bit_cast(float, (unsigned)s << 16);
}
__device__ __forceinline__ float sigm(float v) { return 1.f / (1.f + __expf(-v)); }

// ---------------- elementwise / reduction kernels ----------------

// fused hidden f32 -> bf16 + per-column sum|h| (256 blocks x 32 rows, float4 loads)
__global__ void k_hidact(const float* __restrict__ hidden, u16* __restrict__ hB,
                         float* __restrict__ act) {
  const int t = threadIdx.x;                 // 256: col block t*4
  const int r0 = blockIdx.x * 32;
  float s0 = 0, s1 = 0, s2 = 0, s3 = 0;
  for (int r = 0; r < 32; ++r) {
    const size_t i = (size_t)(r0 + r) * H_ + t * 4;
    float4 v = *(const float4*)&hidden[i];
    s0 += fabsf(v.x); s1 += fabsf(v.y); s2 += fabsf(v.z); s3 += fabsf(v.w);
    ushort4 o;
    o.x = f2bf(v.x); o.y = f2bf(v.y); o.z = f2bf(v.z); o.w = f2bf(v.w);
    *(ushort4*)&hB[i] = o;
  }
  atomicAdd(&act[t * 4], s0); atomicAdd(&act[t * 4 + 1], s1);
  atomicAdd(&act[t * 4 + 2], s2); atomicAdd(&act[t * 4 + 3], s3);
}

struct ConvPs {
  const float* s[9];
  u16* d[9];
  int n4[9];
  // cs slice (blockIdx.y == 9): runs after hidact (prior launch), act is ready
  const float* act;
  const float* strength;
  const float* decay;
  const float* hist;
  float* cs;
};

// all f32->bf16 conversions (8 weights + x) + connection-strength, one launch
__global__ void k_conv10(ConvPs p) {
  const int e = blockIdx.y;
  if (e == 9) {
    if (blockIdx.x < 4) {
      int h = blockIdx.x * 256 + threadIdx.x;
      float ch = p.hist[h] * p.decay[0] + p.act[h] * (1.f / (float)B_);
      p.cs[h] = p.strength[h] * sigm(ch);
    }
    return;
  }
  const int n4 = p.n4[e];
  const float4* s = (const float4*)p.s[e];
  ushort4* d = (ushort4*)p.d[e];
  for (int i = blockIdx.x * 256 + threadIdx.x; i < n4; i += 2048 * 256) {
    float4 v = s[i];
    ushort4 o;
    o.x = f2bf(v.x); o.y = f2bf(v.y); o.z = f2bf(v.z); o.w = f2bf(v.w);
    d[i] = o;
  }
}

// ---------------- GEMM epilogues (vectorized: lane owns 4 consecutive cols) ----------------

struct GemmPs {
  const u16* Bm[4];
  const float* bias[4];
  const float* hidden;   // f32 [B,1024]
  const u16* updB;       // bf16 update (input to EPI3)
  const float* cs;       // [1024]
  const u16* haB;        // bf16 ha (input to EPI2 z=0)
  u16* rhaB;             // bf16 reset*ha  (EPI2 z=0 out)
  u16* upd_out;          // bf16 update    (EPI2 z=1 out)
  u16* hn_bf16;          // EPI3
  float* hp;             // EPI3: row-sum of hn (atomicAdd), scaled 1/H at use
  u16* haB_out;          // EPI1
  u16* out_b[4];         // EPI4 gate logits bf16 [B,2048]
};

// returns per-call row-sum contribution (EPI3 only; else 0)
template <int EPI>
__device__ __forceinline__ float epiV(int row, int col0, f32x4 v, int z, const GemmPs& e) {
  if constexpr (EPI == 1) {            // attention -> ha (bf16)
    float4 bi = *(const float4*)&e.bias[0][col0];
    size_t i = (size_t)row * H_ + col0;
    float4 hd = *(const float4*)&e.hidden[i];
    ushort4 o;
    o.x = f2bf(hd.x * sigm(v[0] + bi.x));
    o.y = f2bf(hd.y * sigm(v[1] + bi.y));
    o.z = f2bf(hd.z * sigm(v[2] + bi.z));
    o.w = f2bf(hd.w * sigm(v[3] + bi.w));
    *(ushort4*)&e.haB_out[i] = o;
    return 0.f;
  } else if constexpr (EPI == 2) {     // z=0: reset*ha bf16; z=1: update bf16
    size_t i = (size_t)row * H_ + col0;
    if (z == 0) {
      float4 bi = *(const float4*)&e.bias[0][col0];
      ushort4 h = *(const ushort4*)&e.haB[i];
      ushort4 o;
      o.x = f2bf((v[0] + bi.x) * bf2f(h.x));
      o.y = f2bf((v[1] + bi.y) * bf2f(h.y));
      o.z = f2bf((v[2] + bi.z) * bf2f(h.z));
      o.w = f2bf((v[3] + bi.w) * bf2f(h.w));
      *(ushort4*)&e.rhaB[i] = o;
    } else {
      float4 bi = *(const float4*)&e.bias[1][col0];
      ushort4 o;
      o.x = f2bf(v[0] + bi.x); o.y = f2bf(v[1] + bi.y);
      o.z = f2bf(v[2] + bi.z); o.w = f2bf(v[3] + bi.w);
      *(ushort4*)&e.upd_out[i] = o;
    }
    return 0.f;
  } else if constexpr (EPI == 3) {     // new -> hidden_new (bf16 store + f32 row-sum)
    float4 bi = *(const float4*)&e.bias[0][col0];
    size_t i = (size_t)row * H_ + col0;
    ushort4 uq = *(const ushort4*)&e.updB[i];
    float4 hd = *(const float4*)&e.hidden[i];
    float4 c4 = *(const float4*)&e.cs[col0];
    float ux = bf2f(uq.x), uy = bf2f(uq.y), uz = bf2f(uq.z), uw = bf2f(uq.w);
    float hx = (1.f - ux) * hd.x + ux * (v[0] + bi.x) * c4.x;
    float hy = (1.f - uy) * hd.y + uy * (v[1] + bi.y) * c4.y;
    float hz = (1.f - uz) * hd.z + uz * (v[2] + bi.z) * c4.z;
    float hw = (1.f - uw) * hd.w + uw * (v[3] + bi.w) * c4.w;
    ushort4 o;
    o.x = f2bf(hx); o.y = f2bf(hy); o.z = f2bf(hz); o.w = f2bf(hw);
    *(ushort4*)&e.hn_bf16[i] = o;
    return hx + hy + hz + hw;
  } else {                             // gate logits bf16
    float4 bi = *(const float4*)&e.bias[z][col0];
    ushort4 o;
    o.x = f2bf(v[0] + bi.x); o.y = f2bf(v[1] + bi.y);
    o.z = f2bf(v[2] + bi.z); o.w = f2bf(v[3] + bi.w);
    *(ushort4*)&e.out_b[z][(size_t)row * P_ + col0] = o;
    return 0.f;
  }
}

// ---------------- gemm_bt: proven 128x128 / BK=64 / 4-wave structure ----------------
// C[M,N] = A[M,K] * B[N,K]^T, K = (NT0+NT1)*64. A row stride H_ (compile-time);
// B row stride KB (compile-time). A K-split realized as two sequential loops.
// Operand-SWAPPED mfma(b,a): lane holds m=r15, n = g*4+reg -> vector epilogue stores.
// LDS XOR-swizzle slot^(row&7) via pre-swizzled global source (linear LDS dest).

template <int EPI, int KB, int NT0, int NT1>
__global__ __launch_bounds__(256, 2) void gemm_bt(const u16* __restrict__ A0,
                                                  const u16* __restrict__ A1,
                                                  GemmPs e) {
  const int z = blockIdx.z;
  const u16* __restrict__ Bm = e.Bm[z];
  __shared__ u16 As[128 * 64];
  __shared__ u16 Bs[128 * 64];
  const int lane = threadIdx.x & 63;
  const int w = threadIdx.x >> 6;
  const int wr = w >> 1, wc = w & 1;
  const int m0 = blockIdx.x * 128, n0 = blockIdx.y * 128;

  f32x4 acc[4][4] = {};

  const int rA = lane >> 3;
  const int srcSlot8 = ((lane & 7) ^ (rA & 7)) << 3;
  const int g = lane >> 4;
  const int r15 = lane & 15;
  const int rx = lane & 7;

  const u16* pA0 = A0 + (size_t)(m0 + w * 32 + rA) * H_ + srcSlot8;
  const u16* pA1 = A1 + (size_t)(m0 + w * 32 + rA) * H_ + srcSlot8;
  const u16* pB  = Bm + (size_t)(n0 + w * 32 + rA) * KB + srcSlot8;

  auto ktile = [&](const u16* pAk, const u16* pBk) {
#pragma unroll
    for (int j = 0; j < 4; ++j) {
      __builtin_amdgcn_global_load_lds((gp1_t)(pAk + (size_t)(j * 8) * H_),
                                       (lp3_t)&As[(w * 32 + j * 8) * 64], 16, 0, 0);
      __builtin_amdgcn_global_load_lds((gp1_t)(pBk + (size_t)(j * 8) * KB),
                                       (lp3_t)&Bs[(w * 32 + j * 8) * 64], 16, 0, 0);
    }
    asm volatile("s_waitcnt vmcnt(0)" ::: "memory");
    __syncthreads();
#pragma unroll
    for (int kk = 0; kk < 2; ++kk) {
      const int cswz = (((g + kk * 4) ^ rx) << 3);
      bfrag af[4], bq[4];
#pragma unroll
      for (int i = 0; i < 4; ++i) {
        af[i] = *(const bfrag*)&As[(wr * 64 + i * 16 + r15) * 64 + cswz];
        bq[i] = *(const bfrag*)&Bs[(wc * 64 + i * 16 + r15) * 64 + cswz];
      }
#pragma unroll
      for (int mi = 0; mi < 4; ++mi)
#pragma unroll
        for (int ni = 0; ni < 4; ++ni)
          acc[mi][ni] = __builtin_amdgcn_mfma_f32_16x16x32_bf16(bq[ni], af[mi], acc[mi][ni], 0, 0, 0);
    }
    __syncthreads();
  };

  for (int t = 0; t < NT0; ++t) ktile(pA0 + t * 64, pB + t * 64);
  if constexpr (NT1 > 0)
    for (int t = 0; t < NT1; ++t) ktile(pA1 + t * 64, pB + (NT0 + t) * 64);

  // swapped layout: m = r15 + mi*16, n = g*4 + reg + ni*16 (4 consecutive cols per lane)
  if constexpr (EPI == 3) {
    float rsum[4];
#pragma unroll
    for (int mi = 0; mi < 4; ++mi) {
      rsum[mi] = 0.f;
#pragma unroll
      for (int ni = 0; ni < 4; ++ni)
        rsum[mi] += epiV<EPI>(m0 + wr * 64 + mi * 16 + r15,
                              n0 + wc * 64 + ni * 16 + g * 4, acc[mi][ni], z, e);
    }
#pragma unroll
    for (int mi = 0; mi < 4; ++mi) {
      float s = rsum[mi];
      s += __shfl_xor(s, 16);
      s += __shfl_xor(s, 32);
      if (g == 0) atomicAdd(&e.hp[m0 + wr * 64 + mi * 16 + r15], s);
    }
  } else {
#pragma unroll
    for (int mi = 0; mi < 4; ++mi)
#pragma unroll
      for (int ni = 0; ni < 4; ++ni)
        epiV<EPI>(m0 + wr * 64 + mi * 16 + r15,
                  n0 + wc * 64 + ni * 16 + g * 4, acc[mi][ni], z, e);
  }
}

// ---------------- final: softmax(addr), sigmoids, memory_new, hidden_final ----------------
// single pass: each thread owns 8 consecutive P-columns in registers.

__global__ __launch_bounds__(256) void k_final(
    const u16* __restrict__ aL, const u16* __restrict__ rL,
    const u16* __restrict__ wL, const u16* __restrict__ fL,
    const float* __restrict__ pm, const u16* __restrict__ hnB,
    const float* __restrict__ hp, float* __restrict__ outH, float* __restrict__ outM) {
  __shared__ float red[8];
  const int row = blockIdx.x, t = threadIdx.x;
  const size_t base = (size_t)row * P_ + t * 8;

  ushort4 a0 = *(const ushort4*)&aL[base];
  ushort4 a1 = *(const ushort4*)&aL[base + 4];
  float av[8] = {bf2f(a0.x), bf2f(a0.y), bf2f(a0.z), bf2f(a0.w),
                 bf2f(a1.x), bf2f(a1.y), bf2f(a1.z), bf2f(a1.w)};
  float lm = av[0];
#pragma unroll
  for (int j = 1; j < 8; ++j) lm = fmaxf(lm, av[j]);
#pragma unroll
  for (int o = 32; o; o >>= 1) lm = fmaxf(lm, __shfl_xor(lm, o));
  if ((t & 63) == 0) red[t >> 6] = lm;
  __syncthreads();
  const float bmax = fmaxf(fmaxf(red[0], red[1]), fmaxf(red[2], red[3]));

  float ev[8];
  float ls = 0.f;
#pragma unroll
  for (int j = 0; j < 8; ++j) { ev[j] = __expf(av[j] - bmax); ls += ev[j]; }
#pragma unroll
  for (int o = 32; o; o >>= 1) ls += __shfl_xor(ls, o);
  if ((t & 63) == 0) red[4 + (t >> 6)] = ls;
  __syncthreads();
  const float inv = 1.f / (red[4] + red[5] + red[6] + red[7]);
  const float hpv = hp[row] * (1.f / (float)H_);

  ushort4 r0 = *(const ushort4*)&rL[base], r1 = *(const ushort4*)&rL[base + 4];
  ushort4 w0 = *(const ushort4*)&wL[base], w1 = *(const ushort4*)&wL[base + 4];
  ushort4 f0 = *(const ushort4*)&fL[base], f1 = *(const ushort4*)&fL[base + 4];
  float4 p0 = *(const float4*)&pm[base], p1 = *(const float4*)&pm[base + 4];
  float rv[8] = {bf2f(r0.x), bf2f(r0.y), bf2f(r0.z), bf2f(r0.w),
                 bf2f(r1.x), bf2f(r1.y), bf2f(r1.z), bf2f(r1.w)};
  float wv[8] = {bf2f(w0.x), bf2f(w0.y), bf2f(w0.z), bf2f(w0.w),
                 bf2f(w1.x), bf2f(w1.y), bf2f(w1.z), bf2f(w1.w)};
  float fv[8] = {bf2f(f0.x), bf2f(f0.y), bf2f(f0.z), bf2f(f0.w),
                 bf2f(f1.x), bf2f(f1.y), bf2f(f1.z), bf2f(f1.w)};
  float pv[8] = {p0.x, p0.y, p0.z, p0.w, p1.x, p1.y, p1.z, p1.w};
  float mem[8];
  float rs = 0.f;
#pragma unroll
  for (int j = 0; j < 8; ++j) {
    mem[j] = sigm(fv[j]) * pv[j] + sigm(wv[j]) * hpv * (ev[j] * inv);
    rs += sigm(rv[j]) * mem[j];
  }
  float4 m0v = {mem[0], mem[1], mem[2], mem[3]};
  float4 m1v = {mem[4], mem[5], mem[6], mem[7]};
  *(float4*)&outM[base] = m0v;
  *(float4*)&outM[base + 4] = m1v;
#pragma unroll
  for (int o = 32; o; o >>= 1) rs += __shfl_xor(rs, o);
  __syncthreads();
  if ((t & 63) == 0) red[t >> 6] = rs;
  __syncthreads();
  const float mean = (red[0] + red[1] + red[2] + red[3]) * (1.f / (float)P_);
  const size_t hb = (size_t)row * H_ + t * 4;
  ushort4 h4 = *(const ushort4*)&hnB[hb];
  float4 o4;
  o4.x = bf2f(h4.x) + mean; o4.y = bf2f(h4.y) + mean;
  o4.z = bf2f(h4.z) + mean; o4.w = bf2f(h4.w) + mean;
  *(float4*)&outH[hb] = o4;
}

// ---------------- host ----------------

extern "C" void kernel_launch(void* const* d_in, const int* in_sizes, int n_in,
                              void* d_out, int out_size, void* d_ws, size_t ws_size,
                              hipStream_t stream) {
  (void)in_sizes; (void)n_in; (void)out_size; (void)ws_size;
  const float* x       = (const float*)d_in[0];
  const float* hidden  = (const float*)d_in[1];
  const float* pm      = (const float*)d_in[2];
  const float* Wa      = (const float*)d_in[3];
  const float* ba      = (const float*)d_in[4];
  const float* Wr      = (const float*)d_in[5];
  const float* br      = (const float*)d_in[6];
  const float* Wu      = (const float*)d_in[7];
  const float* bu      = (const float*)d_in[8];
  const float* Wn      = (const float*)d_in[9];
  const float* bn      = (const float*)d_in[10];
  const float* Wread   = (const float*)d_in[11];
  const float* bread   = (const float*)d_in[12];
  const float* Wwrite  = (const float*)d_in[13];
  const float* bwrite  = (const float*)d_in[14];
  const float* Wforget = (const float*)d_in[15];
  const float* bforget = (const float*)d_in[16];
  const float* Waddr   = (const float*)d_in[17];
  const float* baddr   = (const float*)d_in[18];
  const float* cstr    = (const float*)d_in[19];
  const float* cdecay  = (const float*)d_in[20];
  const float* chist   = (const float*)d_in[21];

  char* wsp = (char*)d_ws;
  auto take = [&](size_t n) { char* p = wsp; wsp += (n + 255) & ~(size_t)255; return p; };
  float* act    = (float*)take((size_t)H_ * 4);          // zeroed (with hp) each call
  float* hp     = (float*)take((size_t)B_ * 4);          // row-sums of hn (atomic)
  float* cs     = (float*)take((size_t)H_ * 4);
  u16* hiddenB  = (u16*)take((size_t)B_ * H_ * 2);       // later reused as hidden_new bf16
  u16* xB       = (u16*)take((size_t)B_ * H_ * 2);
  u16* haB      = (u16*)take((size_t)B_ * H_ * 2);
  u16* rhaB     = (u16*)take((size_t)B_ * H_ * 2);
  u16* updB     = (u16*)take((size_t)B_ * H_ * 2);
  u16* WaB      = (u16*)take((size_t)H_ * H_ * 2);
  u16* WrB      = (u16*)take((size_t)H_ * 2048 * 2);
  u16* WuB      = (u16*)take((size_t)H_ * 2048 * 2);
  u16* WnB      = (u16*)take((size_t)H_ * 2048 * 2);
  u16* WadB     = (u16*)take((size_t)P_ * H_ * 2);
  u16* WrdB     = (u16*)take((size_t)P_ * H_ * 2);
  u16* WwrB     = (u16*)take((size_t)P_ * H_ * 2);
  u16* WfgB     = (u16*)take((size_t)P_ * H_ * 2);
  u16* gAd      = (u16*)take((size_t)B_ * P_ * 2);
  u16* gRd      = (u16*)take((size_t)B_ * P_ * 2);
  u16* gWr      = (u16*)take((size_t)B_ * P_ * 2);
  u16* gFg      = (u16*)take((size_t)B_ * P_ * 2);

  float* outH = (float*)d_out;
  float* outM = outH + (size_t)B_ * H_;

  // zero act + hp (adjacent, single memset)
  hipMemsetAsync(act, 0, (size_t)H_ * 4 + (size_t)B_ * 4, stream);
  // fused hidden->bf16 + column |h| sums (256 blocks: full CU coverage)
  k_hidact<<<dim3(256), dim3(256), 0, stream>>>(hidden, hiddenB, act);

  // all conversions + connection-strength in one launch (cs slice ordered after hidact)
  {
    ConvPs p;
    const float* ss[9] = {Wa, Wr, Wu, Wn, Waddr, Wread, Wwrite, Wforget, x};
    u16* dd[9] = {WaB, WrB, WuB, WnB, WadB, WrdB, WwrB, WfgB, xB};
    int nn[9] = {H_ * H_ / 4, H_ * 2048 / 4, H_ * 2048 / 4, H_ * 2048 / 4,
                 P_ * H_ / 4, P_ * H_ / 4, P_ * H_ / 4, P_ * H_ / 4, B_ * H_ / 4};
    for (int i = 0; i < 9; ++i) { p.s[i] = ss[i]; p.d[i] = dd[i]; p.n4[i] = nn[i]; }
    p.act = act; p.strength = cstr; p.decay = cdecay; p.hist = chist; p.cs = cs;
    k_conv10<<<dim3(2048, 10), dim3(256), 0, stream>>>(p);
  }

  // GEMM 1: attention -> ha bf16
  {
    GemmPs e{};
    e.Bm[0] = WaB; e.bias[0] = ba; e.hidden = hidden; e.haB_out = haB;
    gemm_bt<1, 1024, 16, 0><<<dim3(64, 8, 1), dim3(256), 0, stream>>>(hiddenB, hiddenB, e);
  }
  // GEMM 2/3: z=0 reset -> rha bf16; z=1 update bf16. A = [x | ha]
  {
    GemmPs e{};
    e.Bm[0] = WrB; e.Bm[1] = WuB; e.bias[0] = br; e.bias[1] = bu;
    e.haB = haB; e.rhaB = rhaB; e.upd_out = updB;
    gemm_bt<2, 2048, 16, 16><<<dim3(64, 8, 2), dim3(256), 0, stream>>>(xB, haB, e);
  }
  // GEMM 4: new -> hidden_new bf16 + fused row-sum (hp). A = [x | rha]
  {
    GemmPs e{};
    e.Bm[0] = WnB; e.bias[0] = bn; e.hidden = hidden; e.updB = updB; e.cs = cs;
    e.hn_bf16 = hiddenB; e.hp = hp;
    gemm_bt<3, 2048, 16, 16><<<dim3(64, 8, 1), dim3(256), 0, stream>>>(xB, rhaB, e);
  }
  // GEMMs 5-8: gate logits (addr, read, write, forget)
  {
    GemmPs e{};
    e.Bm[0] = WadB; e.Bm[1] = WrdB; e.Bm[2] = WwrB; e.Bm[3] = WfgB;
    e.bias[0] = baddr; e.bias[1] = bread; e.bias[2] = bwrite; e.bias[3] = bforget;
    e.out_b[0] = gAd; e.out_b[1] = gRd; e.out_b[2] = gWr; e.out_b[3] = gFg;
    gemm_bt<4, 1024, 16, 0><<<dim3(64, 16, 4), dim3(256), 0, stream>>>(hiddenB, hiddenB, e);
  }
  // final fused softmax / gates / outputs
  k_final<<<dim3(B_), dim3(256), 0, stream>>>(gAd, gRd, gWr, gFg, pm, hiddenB, hp, outH, outM);
}